// Round 1
// baseline (20629.054 us; speedup 1.0000x reference)
//
#include <hip/hip_runtime.h>
#include <cmath>

#define S 4096
#define HID 768
#define NH 12
#define DH 64
#define CHUNK 256
#define NC (S / CHUNK)
#define NG 16
#define FF 3072
#define NLAYER 12
#define QKV3 (3 * HID)
#define NEGV -1e9f

// ---------------- block reduction helpers (blockDim.x == 256) ----------------
__device__ __forceinline__ float block_reduce_sum(float v, float* red) {
  int t = threadIdx.x;
  red[t] = v; __syncthreads();
  for (int st = 128; st > 0; st >>= 1) {
    if (t < st) red[t] += red[t + st];
    __syncthreads();
  }
  float r = red[0]; __syncthreads();
  return r;
}
__device__ __forceinline__ float block_reduce_max(float v, float* red) {
  int t = threadIdx.x;
  red[t] = v; __syncthreads();
  for (int st = 128; st > 0; st >>= 1) {
    if (t < st) red[t] = fmaxf(red[t], red[t + st]);
    __syncthreads();
  }
  float r = red[0]; __syncthreads();
  return r;
}

// ---------------- gidx / gvalid (matches jax top_k semantics) ----------------
__global__ void gidx_kernel(const int* __restrict__ gmask, int* __restrict__ gidx,
                            float* __restrict__ gvalid) {
  if (threadIdx.x != 0 || blockIdx.x != 0) return;
  int cnt = 0;
  for (int s = 0; s < S && cnt < NG; s++)
    if (gmask[s] > 0) { gidx[cnt] = s; gvalid[cnt] = 1.f; cnt++; }
  for (int s = 0; s < S && cnt < NG; s++)
    if (gmask[s] == 0) { gidx[cnt] = s; gvalid[cnt] = 0.f; cnt++; }
}

// ---------------- embedding + LayerNorm ----------------
__global__ __launch_bounds__(256) void embed_ln_kernel(
    const int* __restrict__ ids, const float* __restrict__ tok,
    const float* __restrict__ pos, const float* __restrict__ g,
    const float* __restrict__ b, float* __restrict__ h) {
  int s = blockIdx.x, t = threadIdx.x;
  __shared__ float xs[HID];
  __shared__ float red[256];
  const float* tr = tok + (size_t)ids[s] * HID;
  const float* pr = pos + (size_t)s * HID;
  float ls = 0.f;
  for (int i = t; i < HID; i += 256) { float v = tr[i] + pr[i]; xs[i] = v; ls += v; }
  float mu = block_reduce_sum(ls, red) * (1.f / HID);
  float lv = 0.f;
  for (int i = t; i < HID; i += 256) { float d = xs[i] - mu; lv += d * d; }
  float var = block_reduce_sum(lv, red) * (1.f / HID);
  float inv = rsqrtf(var + 1e-5f);
  for (int i = t; i < HID; i += 256)
    h[(size_t)s * HID + i] = (xs[i] - mu) * inv * g[i] + b[i];
}

// ---------------- residual add + LayerNorm (in-place on h) ----------------
__global__ __launch_bounds__(256) void add_ln_kernel(
    float* __restrict__ h, const float* __restrict__ x2,
    const float* __restrict__ g, const float* __restrict__ b) {
  int s = blockIdx.x, t = threadIdx.x;
  __shared__ float xs[HID];
  __shared__ float red[256];
  float ls = 0.f;
  for (int i = t; i < HID; i += 256) {
    float v = h[(size_t)s * HID + i] + x2[(size_t)s * HID + i];
    xs[i] = v; ls += v;
  }
  float mu = block_reduce_sum(ls, red) * (1.f / HID);
  float lv = 0.f;
  for (int i = t; i < HID; i += 256) { float d = xs[i] - mu; lv += d * d; }
  float var = block_reduce_sum(lv, red) * (1.f / HID);
  float inv = rsqrtf(var + 1e-5f);
  for (int i = t; i < HID; i += 256)
    h[(size_t)s * HID + i] = (xs[i] - mu) * inv * g[i] + b[i];
}

// ---------------- fp32 tiled GEMM: C = A(MxK) @ B(KxN) + bias, opt GELU ----------------
#define BM 128
#define BN 128
#define BK 16

template <bool GELU>
__global__ __launch_bounds__(256) void gemm_bias_kernel(
    const float* __restrict__ A, const float* __restrict__ B,
    const float* __restrict__ bias, float* __restrict__ C, int M, int N, int K) {
  __shared__ __align__(16) float As[BK][BM];  // transposed A tile
  __shared__ __align__(16) float Bs[BK][BN];
  int t = threadIdx.x;
  int bx = blockIdx.x, by = blockIdx.y;
  int tx = t & 15, ty = t >> 4;
  float acc[8][8] = {};
  int ar = t >> 1, ak = (t & 1) * 8;       // A: 128 rows x 16 k, 8 floats/thread
  int brow = t >> 4, bcol = (t & 15) * 8;  // B: 16 rows x 128 cols, 8 floats/thread
  const float* Ap = A + (size_t)(by * BM + ar) * K + ak;
  const float* Bp = B + (size_t)brow * N + (size_t)bx * BN + bcol;
  for (int k0 = 0; k0 < K; k0 += BK) {
    float4 a0 = *(const float4*)(Ap + k0);
    float4 a1 = *(const float4*)(Ap + k0 + 4);
    float4 b0 = *(const float4*)(Bp + (size_t)k0 * N);
    float4 b1 = *(const float4*)(Bp + (size_t)k0 * N + 4);
    As[ak + 0][ar] = a0.x; As[ak + 1][ar] = a0.y; As[ak + 2][ar] = a0.z; As[ak + 3][ar] = a0.w;
    As[ak + 4][ar] = a1.x; As[ak + 5][ar] = a1.y; As[ak + 6][ar] = a1.z; As[ak + 7][ar] = a1.w;
    *(float4*)&Bs[brow][bcol] = b0;
    *(float4*)&Bs[brow][bcol + 4] = b1;
    __syncthreads();
#pragma unroll
    for (int kk = 0; kk < BK; kk++) {
      float a[8], b[8];
      *(float4*)&a[0] = *(const float4*)&As[kk][ty * 8];
      *(float4*)&a[4] = *(const float4*)&As[kk][ty * 8 + 4];
      *(float4*)&b[0] = *(const float4*)&Bs[kk][tx * 8];
      *(float4*)&b[4] = *(const float4*)&Bs[kk][tx * 8 + 4];
#pragma unroll
      for (int i = 0; i < 8; i++)
#pragma unroll
        for (int j = 0; j < 8; j++) acc[i][j] += a[i] * b[j];
    }
    __syncthreads();
  }
#pragma unroll
  for (int i = 0; i < 8; i++) {
    int row = by * BM + ty * 8 + i;
    float* crow = C + (size_t)row * N + (size_t)bx * BN + tx * 8;
#pragma unroll
    for (int j0 = 0; j0 < 8; j0 += 4) {
      float vals[4];
#pragma unroll
      for (int jj = 0; jj < 4; jj++) {
        float x = acc[i][j0 + jj] + bias[bx * BN + tx * 8 + j0 + jj];
        if (GELU) x = 0.5f * x * (1.f + erff(x * 0.70710678118654752f));
        vals[jj] = x;
      }
      float4 o = {vals[0], vals[1], vals[2], vals[3]};
      *(float4*)(crow + j0) = o;
    }
  }
}

// ---------------- local (windowed) attention, one block per (head, chunk) ----------------
__global__ __launch_bounds__(256) void local_attn_kernel(
    const float* __restrict__ qkv, const int* __restrict__ amask,
    const int* __restrict__ gmask, const int* __restrict__ gidx,
    const float* __restrict__ gvalid, float* __restrict__ outp) {
  int h = blockIdx.x / NC, ci = blockIdx.x % NC;
  int p = threadIdx.x;
  int s0 = ci * CHUNK + p;
  __shared__ __align__(16) float kt[64][64];
  __shared__ __align__(16) float vt[64][64];
  __shared__ __align__(16) float kg[NG][64];
  __shared__ __align__(16) float vg[NG][64];
  __shared__ float kok[64];
  __shared__ float gvs[NG];

  float q[64];
  {
    const float* qr = qkv + (size_t)s0 * QKV3 + h * DH;
#pragma unroll
    for (int d = 0; d < 64; d += 4) {
      float4 v4 = *(const float4*)(qr + d);
      q[d] = v4.x * 0.125f; q[d + 1] = v4.y * 0.125f;
      q[d + 2] = v4.z * 0.125f; q[d + 3] = v4.w * 0.125f;
    }
  }
  {  // stage the 16 global K/V rows
    int g = threadIdx.x >> 4;
    int d0 = (threadIdx.x & 15) * 4;
    int sg = gidx[g];
    const float* kr = qkv + (size_t)sg * QKV3 + HID + h * DH + d0;
    *(float4*)&kg[g][d0] = *(const float4*)kr;
    *(float4*)&vg[g][d0] = *(const float4*)(kr + HID);
    if (threadIdx.x < NG) gvs[threadIdx.x] = gvalid[threadIdx.x];
  }

  float mb = -1e30f, l = 0.f;
  float acc[64];
#pragma unroll
  for (int d = 0; d < 64; d++) acc[d] = 0.f;

  for (int jt = 0; jt < 12; jt++) {  // 768 window keys, 64 at a time
    __syncthreads();
    int jl = threadIdx.x >> 2;
    int prt = (threadIdx.x & 3) * 16;
    int jj = jt * 64 + jl;
    int gk = ci * CHUNK + jj - CHUNK;
    if (gk >= 0 && gk < S) {
      const float* kr = qkv + (size_t)gk * QKV3 + HID + h * DH + prt;
      const float* vr = kr + HID;
#pragma unroll
      for (int j = 0; j < 4; j++) {
        *(float4*)&kt[jl][prt + j * 4] = *(const float4*)(kr + j * 4);
        *(float4*)&vt[jl][prt + j * 4] = *(const float4*)(vr + j * 4);
      }
    }
    if ((threadIdx.x & 3) == 0)
      kok[jl] = (gk >= 0 && gk < S && amask[gk] != 0 && gmask[gk] == 0) ? 1.f : 0.f;
    __syncthreads();
#pragma unroll 1
    for (int j2 = 0; j2 < 64; j2++) {
      int jj2 = jt * 64 + j2;
      int diff = jj2 - CHUNK - p;
      if (kok[j2] > 0.f && diff >= -CHUNK && diff <= CHUNK) {
        float s = 0.f;
#pragma unroll
        for (int d = 0; d < 64; d += 4) {
          float4 kv = *(const float4*)&kt[j2][d];
          s += q[d] * kv.x + q[d + 1] * kv.y + q[d + 2] * kv.z + q[d + 3] * kv.w;
        }
        if (s > mb + 8.f) {  // deferred-max rescale
          float corr = __expf(mb - s);
          mb = s; l *= corr;
#pragma unroll
          for (int d = 0; d < 64; d++) acc[d] *= corr;
        }
        float pj = __expf(s - mb);
        l += pj;
#pragma unroll
        for (int d = 0; d < 64; d += 4) {
          float4 vv = *(const float4*)&vt[j2][d];
          acc[d] += pj * vv.x; acc[d + 1] += pj * vv.y;
          acc[d + 2] += pj * vv.z; acc[d + 3] += pj * vv.w;
        }
        // (exp(NEG-m) underflows to exactly 0 in fp32, so skipping == reference)
      }
    }
  }
#pragma unroll 1
  for (int g = 0; g < NG; g++) {  // global key slots
    if (gvs[g] > 0.f) {
      float s = 0.f;
#pragma unroll
      for (int d = 0; d < 64; d += 4) {
        float4 kv = *(const float4*)&kg[g][d];
        s += q[d] * kv.x + q[d + 1] * kv.y + q[d + 2] * kv.z + q[d + 3] * kv.w;
      }
      if (s > mb + 8.f) {
        float corr = __expf(mb - s);
        mb = s; l *= corr;
#pragma unroll
        for (int d = 0; d < 64; d++) acc[d] *= corr;
      }
      float pj = __expf(s - mb);
      l += pj;
#pragma unroll
      for (int d = 0; d < 64; d += 4) {
        float4 vv = *(const float4*)&vg[g][d];
        acc[d] += pj * vv.x; acc[d + 1] += pj * vv.y;
        acc[d + 2] += pj * vv.z; acc[d + 3] += pj * vv.w;
      }
    }
  }
  float inv = (l > 0.f) ? 1.f / l : 0.f;
  float* orow = outp + (size_t)s0 * HID + h * DH;
#pragma unroll
  for (int d = 0; d < 64; d += 4) {
    float4 o4 = {acc[d] * inv, acc[d + 1] * inv, acc[d + 2] * inv, acc[d + 3] * inv};
    *(float4*)(orow + d) = o4;
  }
}

// ---------------- global-token full attention, one block per (head, g) ----------------
__global__ __launch_bounds__(256) void global_attn_kernel(
    const float* __restrict__ qkv, const int* __restrict__ amask,
    const int* __restrict__ gidx, const float* __restrict__ gvalid,
    float* __restrict__ outp) {
  int h = blockIdx.x / NG, g = blockIdx.x % NG;
  if (gvalid[g] <= 0.f) return;  // uniform across block
  int sg = gidx[g];
  __shared__ float qs[DH];
  __shared__ float sc[S];
  __shared__ float red[256];
  int t = threadIdx.x;
  if (t < DH) qs[t] = qkv[(size_t)sg * QKV3 + h * DH + t] * 0.125f;
  __syncthreads();
  float lmax = -1e30f;
  for (int ji = 0; ji < S / 256; ji++) {
    int j = ji * 256 + t;
    float s;
    if (amask[j] != 0) {
      s = 0.f;
      const float4* kr4 = (const float4*)(qkv + (size_t)j * QKV3 + HID + h * DH);
#pragma unroll
      for (int d4 = 0; d4 < 16; d4++) {
        float4 kv = kr4[d4];
        s += qs[d4 * 4] * kv.x + qs[d4 * 4 + 1] * kv.y +
             qs[d4 * 4 + 2] * kv.z + qs[d4 * 4 + 3] * kv.w;
      }
    } else s = NEGV;
    sc[j] = s;
    lmax = fmaxf(lmax, s);
  }
  float mm = block_reduce_max(lmax, red);
  float lsum = 0.f;
  for (int ji = 0; ji < S / 256; ji++) {
    int j = ji * 256 + t;
    float e = __expf(sc[j] - mm);
    sc[j] = e;
    lsum += e;
  }
  float denom = block_reduce_sum(lsum, red);
  int d = t & 63, grp = t >> 6;
  float o = 0.f;
  for (int j = grp; j < S; j += 4)
    o += sc[j] * qkv[(size_t)j * QKV3 + 2 * HID + h * DH + d];
  __syncthreads();
  red[grp * 64 + d] = o;
  __syncthreads();
  if (t < 64) {
    float oo = red[t] + red[64 + t] + red[128 + t] + red[192 + t];
    outp[(size_t)sg * HID + h * DH + t] = oo / denom;
  }
}

// ---------------- masked mean pool (partials) + classifier head ----------------
__global__ __launch_bounds__(256) void pool_part_kernel(
    const float* __restrict__ h, const int* __restrict__ amask, float* __restrict__ part) {
  int b = blockIdx.x, t = threadIdx.x;
  float a0 = 0.f, a1 = 0.f, a2 = 0.f;
  for (int r = 0; r < 64; r++) {
    int s = b * 64 + r;
    float w = (float)amask[s];
    const float* hr = h + (size_t)s * HID;
    a0 += hr[t] * w;
    a1 += hr[t + 256] * w;
    a2 += hr[t + 512] * w;
  }
  part[(size_t)b * HID + t] = a0;
  part[(size_t)b * HID + t + 256] = a1;
  part[(size_t)b * HID + t + 512] = a2;
}

__global__ __launch_bounds__(256) void cls_head_kernel(
    const float* __restrict__ part, const int* __restrict__ amask,
    const float* __restrict__ clsW, const float* __restrict__ clsb,
    float* __restrict__ out) {
  __shared__ float pooled[HID];
  __shared__ float red[256];
  int t = threadIdx.x;
  for (int i = t; i < HID; i += 256) {
    float s = 0.f;
    for (int b2 = 0; b2 < 64; b2++) s += part[(size_t)b2 * HID + i];
    pooled[i] = s;
  }
  float c = 0.f;
  for (int s2 = t; s2 < S; s2 += 256) c += (float)amask[s2];
  float cnt = block_reduce_sum(c, red);  // barrier also makes pooled[] visible
  float p0 = 0.f, p1 = 0.f;
  for (int i = t; i < HID; i += 256) {
    float pv = pooled[i] / cnt;
    p0 += pv * clsW[i * 2];
    p1 += pv * clsW[i * 2 + 1];
  }
  float s0 = block_reduce_sum(p0, red);
  float s1 = block_reduce_sum(p1, red);
  if (t == 0) { out[0] = s0 + clsb[0]; out[1] = s1 + clsb[1]; }
}

// ---------------- launch ----------------
extern "C" void kernel_launch(void* const* d_in, const int* in_sizes, int n_in,
                              void* d_out, int out_size, void* d_ws, size_t ws_size,
                              hipStream_t stream) {
  const int* ids = (const int*)d_in[0];
  const int* amask = (const int*)d_in[1];
  const int* gmask = (const int*)d_in[2];
  const float* tok = (const float*)d_in[3];
  const float* pos = (const float*)d_in[4];
  const float* elnw = (const float*)d_in[5];
  const float* elnb = (const float*)d_in[6];
  const float* Wqkv = (const float*)d_in[7];
  const float* bqkv = (const float*)d_in[8];
  const float* Wo = (const float*)d_in[9];
  const float* bo = (const float*)d_in[10];
  const float* ln1w = (const float*)d_in[11];
  const float* ln1b = (const float*)d_in[12];
  const float* W1 = (const float*)d_in[13];
  const float* b1 = (const float*)d_in[14];
  const float* W2 = (const float*)d_in[15];
  const float* b2 = (const float*)d_in[16];
  const float* ln2w = (const float*)d_in[17];
  const float* ln2b = (const float*)d_in[18];
  const float* clsW = (const float*)d_in[19];
  const float* clsb = (const float*)d_in[20];

  float* ws = (float*)d_ws;
  float* h = ws;                              // S*HID
  float* buf = h + (size_t)S * HID;           // S*FF  (qkv and ffn share)
  float* attn_o = buf + (size_t)S * FF;       // S*HID
  float* proj = attn_o + (size_t)S * HID;     // S*HID
  float* part = proj + (size_t)S * HID;       // 64*HID
  int* gidx = (int*)(part + 64 * HID);        // NG ints
  float* gvalid = (float*)(gidx + NG);        // NG floats

  gidx_kernel<<<1, 64, 0, stream>>>(gmask, gidx, gvalid);
  embed_ln_kernel<<<S, 256, 0, stream>>>(ids, tok, pos, elnw, elnb, h);
  for (int l = 0; l < NLAYER; l++) {
    gemm_bias_kernel<false><<<dim3(QKV3 / BN, S / BM), 256, 0, stream>>>(
        h, Wqkv + (size_t)l * HID * QKV3, bqkv + (size_t)l * QKV3, buf, S, QKV3, HID);
    local_attn_kernel<<<NH * NC, 256, 0, stream>>>(buf, amask, gmask, gidx, gvalid, attn_o);
    global_attn_kernel<<<NH * NG, 256, 0, stream>>>(buf, amask, gidx, gvalid, attn_o);
    gemm_bias_kernel<false><<<dim3(HID / BN, S / BM), 256, 0, stream>>>(
        attn_o, Wo + (size_t)l * HID * HID, bo + (size_t)l * HID, proj, S, HID, HID);
    add_ln_kernel<<<S, 256, 0, stream>>>(h, proj, ln1w + (size_t)l * HID, ln1b + (size_t)l * HID);
    gemm_bias_kernel<true><<<dim3(FF / BN, S / BM), 256, 0, stream>>>(
        h, W1 + (size_t)l * HID * FF, b1 + (size_t)l * FF, buf, S, FF, HID);
    gemm_bias_kernel<false><<<dim3(HID / BN, S / BM), 256, 0, stream>>>(
        buf, W2 + (size_t)l * FF * HID, b2 + (size_t)l * HID, proj, S, HID, FF);
    add_ln_kernel<<<S, 256, 0, stream>>>(h, proj, ln2w + (size_t)l * HID, ln2b + (size_t)l * HID);
  }
  pool_part_kernel<<<64, 256, 0, stream>>>(h, amask, part);
  cls_head_kernel<<<1, 256, 0, stream>>>(part, amask, clsW, clsb, (float*)d_out);
}

// Round 2
// 11092.263 us; speedup vs baseline: 1.8598x; 1.8598x over previous
//
#include <hip/hip_runtime.h>
#include <cmath>

#define S 4096
#define HID 768
#define NH 12
#define DH 64
#define CHUNK 256
#define NC (S / CHUNK)
#define NG 16
#define FF 3072
#define NLAYER 12
#define QKV3 (3 * HID)
#define NEGV -1e9f

typedef unsigned short u16;
typedef __attribute__((ext_vector_type(4))) unsigned short u16x4;
typedef __attribute__((ext_vector_type(8))) unsigned short u16x8;
typedef __attribute__((ext_vector_type(8))) short bf16x8;
typedef __attribute__((ext_vector_type(4))) float f32x4;

__device__ __forceinline__ u16 f2bf(float x) {  // round-to-nearest-even bf16
  unsigned u = __float_as_uint(x);
  return (u16)((u + 0x7FFFu + ((u >> 16) & 1u)) >> 16);
}
__device__ __forceinline__ u16x8 pack8(float4 a, float4 b) {
  u16x8 r;
  r[0] = f2bf(a.x); r[1] = f2bf(a.y); r[2] = f2bf(a.z); r[3] = f2bf(a.w);
  r[4] = f2bf(b.x); r[5] = f2bf(b.y); r[6] = f2bf(b.z); r[7] = f2bf(b.w);
  return r;
}

// ---------------- block reduction helpers (blockDim.x == 256) ----------------
__device__ __forceinline__ float block_reduce_sum(float v, float* red) {
  int t = threadIdx.x;
  red[t] = v; __syncthreads();
  for (int st = 128; st > 0; st >>= 1) {
    if (t < st) red[t] += red[t + st];
    __syncthreads();
  }
  float r = red[0]; __syncthreads();
  return r;
}
__device__ __forceinline__ float block_reduce_max(float v, float* red) {
  int t = threadIdx.x;
  red[t] = v; __syncthreads();
  for (int st = 128; st > 0; st >>= 1) {
    if (t < st) red[t] = fmaxf(red[t], red[t + st]);
    __syncthreads();
  }
  float r = red[0]; __syncthreads();
  return r;
}

// ---------------- gidx / gvalid (matches jax top_k semantics) ----------------
__global__ void gidx_kernel(const int* __restrict__ gmask, int* __restrict__ gidx,
                            float* __restrict__ gvalid) {
  if (threadIdx.x != 0 || blockIdx.x != 0) return;
  int cnt = 0;
  for (int s = 0; s < S && cnt < NG; s++)
    if (gmask[s] > 0) { gidx[cnt] = s; gvalid[cnt] = 1.f; cnt++; }
  for (int s = 0; s < S && cnt < NG; s++)
    if (gmask[s] == 0) { gidx[cnt] = s; gvalid[cnt] = 0.f; cnt++; }
}

// ---------------- embedding + LayerNorm ----------------
__global__ __launch_bounds__(256) void embed_ln_kernel(
    const int* __restrict__ ids, const float* __restrict__ tok,
    const float* __restrict__ pos, const float* __restrict__ g,
    const float* __restrict__ b, float* __restrict__ h) {
  int s = blockIdx.x, t = threadIdx.x;
  __shared__ float xs[HID];
  __shared__ float red[256];
  const float* tr = tok + (size_t)ids[s] * HID;
  const float* pr = pos + (size_t)s * HID;
  float ls = 0.f;
  for (int i = t; i < HID; i += 256) { float v = tr[i] + pr[i]; xs[i] = v; ls += v; }
  float mu = block_reduce_sum(ls, red) * (1.f / HID);
  float lv = 0.f;
  for (int i = t; i < HID; i += 256) { float d = xs[i] - mu; lv += d * d; }
  float var = block_reduce_sum(lv, red) * (1.f / HID);
  float inv = rsqrtf(var + 1e-5f);
  for (int i = t; i < HID; i += 256)
    h[(size_t)s * HID + i] = (xs[i] - mu) * inv * g[i] + b[i];
}

// ---------------- residual add + LayerNorm (in-place on h) ----------------
__global__ __launch_bounds__(256) void add_ln_kernel(
    float* __restrict__ h, const float* __restrict__ x2,
    const float* __restrict__ g, const float* __restrict__ b) {
  int s = blockIdx.x, t = threadIdx.x;
  __shared__ float xs[HID];
  __shared__ float red[256];
  float ls = 0.f;
  for (int i = t; i < HID; i += 256) {
    float v = h[(size_t)s * HID + i] + x2[(size_t)s * HID + i];
    xs[i] = v; ls += v;
  }
  float mu = block_reduce_sum(ls, red) * (1.f / HID);
  float lv = 0.f;
  for (int i = t; i < HID; i += 256) { float d = xs[i] - mu; lv += d * d; }
  float var = block_reduce_sum(lv, red) * (1.f / HID);
  float inv = rsqrtf(var + 1e-5f);
  for (int i = t; i < HID; i += 256)
    h[(size_t)s * HID + i] = (xs[i] - mu) * inv * g[i] + b[i];
}

// ---------------- weight transpose + bf16 convert: W[K][N] f32 -> WT[N][K] bf16 ----
__global__ __launch_bounds__(256) void wt_kernel(const float* __restrict__ W,
                                                 u16* __restrict__ WT, int K, int N) {
  __shared__ float tile[32][33];
  int k0 = blockIdx.y * 32, n0 = blockIdx.x * 32;
  int t = threadIdx.x;
  int r = t >> 3, c = (t & 7) * 4;
  float4 v = *(const float4*)&W[(size_t)(k0 + r) * N + n0 + c];
  tile[r][c] = v.x; tile[r][c + 1] = v.y; tile[r][c + 2] = v.z; tile[r][c + 3] = v.w;
  __syncthreads();
  int n = t >> 3, kq = (t & 7) * 4;
  u16x4 o;
  o[0] = f2bf(tile[kq][n]);     o[1] = f2bf(tile[kq + 1][n]);
  o[2] = f2bf(tile[kq + 2][n]); o[3] = f2bf(tile[kq + 3][n]);
  *(u16x4*)&WT[(size_t)(n0 + n) * K + k0 + kq] = o;
}

// ---------------- bf16 MFMA GEMM: C = A(f32, MxK) @ BT(bf16, [N][K])^T + bias -----
#define GBM 128
#define GBN 128
#define GBK 32

template <bool GELU>
__global__ __launch_bounds__(256) void gemm_mfma_kernel(
    const float* __restrict__ A, const u16* __restrict__ BT,
    const float* __restrict__ bias, float* __restrict__ C, int M, int N, int K) {
  __shared__ __align__(16) u16 As[GBM * GBK];  // [row][k], 64B rows
  __shared__ __align__(16) u16 Bs[GBN * GBK];  // [n][k]
  int t = threadIdx.x;
  int lane = t & 63, wave = t >> 6;
  int wr = wave >> 1, wc = wave & 1;
  int bx = blockIdx.x, by = blockIdx.y;

  f32x4 acc[4][4];
#pragma unroll
  for (int m = 0; m < 4; m++)
#pragma unroll
    for (int n = 0; n < 4; n++) acc[m][n] = (f32x4){0.f, 0.f, 0.f, 0.f};

  int r0 = t >> 2, kq = t & 3;  // 4 lanes/row, 16B(8 bf16) per lane
  const float* apA = A + (size_t)(by * GBM + r0) * K + kq * 8;
  const u16* bpB = BT + (size_t)(bx * GBN + r0) * K + kq * 8;
  u16* asw = &As[r0 * GBK + kq * 8];
  u16* bsw = &Bs[r0 * GBK + kq * 8];
  const u16* aBase = &As[(wr * 64 + (lane & 15)) * GBK + (lane >> 4) * 8];
  const u16* bBase = &Bs[(wc * 64 + (lane & 15)) * GBK + (lane >> 4) * 8];

  for (int k0 = 0; k0 < K; k0 += GBK) {
    float4 a0 = *(const float4*)(apA + k0);
    float4 a1 = *(const float4*)(apA + k0 + 4);
    float4 a2 = *(const float4*)(apA + (size_t)64 * K + k0);
    float4 a3 = *(const float4*)(apA + (size_t)64 * K + k0 + 4);
    u16x8 bv0 = *(const u16x8*)(bpB + k0);
    u16x8 bv1 = *(const u16x8*)(bpB + (size_t)64 * K + k0);
    *(u16x8*)asw = pack8(a0, a1);
    *(u16x8*)(asw + 64 * GBK) = pack8(a2, a3);
    *(u16x8*)bsw = bv0;
    *(u16x8*)(bsw + 64 * GBK) = bv1;
    __syncthreads();
    bf16x8 af[4], bf_[4];
#pragma unroll
    for (int m = 0; m < 4; m++) af[m] = *(const bf16x8*)(aBase + m * 16 * GBK);
#pragma unroll
    for (int n = 0; n < 4; n++) bf_[n] = *(const bf16x8*)(bBase + n * 16 * GBK);
#pragma unroll
    for (int m = 0; m < 4; m++)
#pragma unroll
      for (int n = 0; n < 4; n++)
        acc[m][n] = __builtin_amdgcn_mfma_f32_16x16x32_bf16(af[m], bf_[n], acc[m][n], 0, 0, 0);
    __syncthreads();
  }

  int row_base = by * GBM + wr * 64 + (lane >> 4) * 4;
  int col_base = bx * GBN + wc * 64 + (lane & 15);
#pragma unroll
  for (int m = 0; m < 4; m++) {
#pragma unroll
    for (int n = 0; n < 4; n++) {
      int col = col_base + n * 16;
      float bs = bias[col];
#pragma unroll
      for (int j = 0; j < 4; j++) {
        int row = row_base + m * 16 + j;
        float x = acc[m][n][j] + bs;
        if (GELU) x = 0.5f * x * (1.f + erff(x * 0.70710678118654752f));
        C[(size_t)row * N + col] = x;
      }
    }
  }
}

// ---------------- local (windowed) attention: block = (head, chunk, q-quarter) ----
__global__ __launch_bounds__(64) void local_attn_kernel(
    const float* __restrict__ qkv, const int* __restrict__ amask,
    const int* __restrict__ gmask, const int* __restrict__ gidx,
    const float* __restrict__ gvalid, float* __restrict__ outp) {
  int bid = blockIdx.x;
  int h = bid >> 6;           // 64 = NC*4 blocks per head
  int rem = bid & 63;
  int ci = rem >> 2, qq = rem & 3;
  int t = threadIdx.x;
  int p = qq * 64 + t;
  int s0 = ci * CHUNK + p;
  __shared__ __align__(16) float kt[64][64];
  __shared__ __align__(16) float vt[64][64];
  __shared__ __align__(16) float kg[NG][64];
  __shared__ __align__(16) float vg[NG][64];
  __shared__ float kok[64];
  __shared__ float gvs[NG];

  float q[64];
  {
    const float* qr = qkv + (size_t)s0 * QKV3 + h * DH;
#pragma unroll
    for (int d = 0; d < 64; d += 4) {
      float4 v4 = *(const float4*)(qr + d);
      q[d] = v4.x * 0.125f; q[d + 1] = v4.y * 0.125f;
      q[d + 2] = v4.z * 0.125f; q[d + 3] = v4.w * 0.125f;
    }
  }
  {  // stage the 16 global K/V rows
    int g = t >> 2, d0 = (t & 3) * 16;
    int sg = gidx[g];
    const float* kr = qkv + (size_t)sg * QKV3 + HID + h * DH + d0;
#pragma unroll
    for (int j = 0; j < 4; j++) {
      *(float4*)&kg[g][d0 + j * 4] = *(const float4*)(kr + j * 4);
      *(float4*)&vg[g][d0 + j * 4] = *(const float4*)(kr + HID + j * 4);
    }
    if (t < NG) gvs[t] = gvalid[t];
  }

  float mb = -1e30f, l = 0.f;
  float acc[64];
#pragma unroll
  for (int d = 0; d < 64; d++) acc[d] = 0.f;

  // quarter qq only needs window keys jj in [qq*64, qq*64+575] -> tiles qq..qq+8
  for (int jt = qq; jt < qq + 9; jt++) {
    __syncthreads();
    {
      int d0 = (t & 3) * 16;
#pragma unroll
      for (int rb = 0; rb < 4; rb++) {
        int row = rb * 16 + (t >> 2);
        int gk = ci * CHUNK + jt * 64 + row - CHUNK;
        if (gk >= 0 && gk < S) {
          const float* kr = qkv + (size_t)gk * QKV3 + HID + h * DH + d0;
          const float* vr = kr + HID;
#pragma unroll
          for (int j = 0; j < 4; j++) {
            *(float4*)&kt[row][d0 + j * 4] = *(const float4*)(kr + j * 4);
            *(float4*)&vt[row][d0 + j * 4] = *(const float4*)(vr + j * 4);
          }
        }
      }
      int gkt = ci * CHUNK + jt * 64 + t - CHUNK;
      kok[t] = (gkt >= 0 && gkt < S && amask[gkt] != 0 && gmask[gkt] == 0) ? 1.f : 0.f;
    }
    __syncthreads();
#pragma unroll 1
    for (int j2 = 0; j2 < 64; j2++) {
      int jj2 = jt * 64 + j2;
      int diff = jj2 - CHUNK - p;
      if (kok[j2] > 0.f && diff >= -CHUNK && diff <= CHUNK) {
        float s = 0.f;
#pragma unroll
        for (int d = 0; d < 64; d += 4) {
          float4 kv = *(const float4*)&kt[j2][d];
          s += q[d] * kv.x + q[d + 1] * kv.y + q[d + 2] * kv.z + q[d + 3] * kv.w;
        }
        if (s > mb + 8.f) {  // deferred-max rescale
          float corr = __expf(mb - s);
          mb = s; l *= corr;
#pragma unroll
          for (int d = 0; d < 64; d++) acc[d] *= corr;
        }
        float pj = __expf(s - mb);
        l += pj;
#pragma unroll
        for (int d = 0; d < 64; d += 4) {
          float4 vv = *(const float4*)&vt[j2][d];
          acc[d] += pj * vv.x; acc[d + 1] += pj * vv.y;
          acc[d + 2] += pj * vv.z; acc[d + 3] += pj * vv.w;
        }
      }
    }
  }
#pragma unroll 1
  for (int g = 0; g < NG; g++) {  // global key slots
    if (gvs[g] > 0.f) {
      float s = 0.f;
#pragma unroll
      for (int d = 0; d < 64; d += 4) {
        float4 kv = *(const float4*)&kg[g][d];
        s += q[d] * kv.x + q[d + 1] * kv.y + q[d + 2] * kv.z + q[d + 3] * kv.w;
      }
      if (s > mb + 8.f) {
        float corr = __expf(mb - s);
        mb = s; l *= corr;
#pragma unroll
        for (int d = 0; d < 64; d++) acc[d] *= corr;
      }
      float pj = __expf(s - mb);
      l += pj;
#pragma unroll
      for (int d = 0; d < 64; d += 4) {
        float4 vv = *(const float4*)&vg[g][d];
        acc[d] += pj * vv.x; acc[d + 1] += pj * vv.y;
        acc[d + 2] += pj * vv.z; acc[d + 3] += pj * vv.w;
      }
    }
  }
  float inv = (l > 0.f) ? 1.f / l : 0.f;
  float* orow = outp + (size_t)s0 * HID + h * DH;
#pragma unroll
  for (int d = 0; d < 64; d += 4) {
    float4 o4 = {acc[d] * inv, acc[d + 1] * inv, acc[d + 2] * inv, acc[d + 3] * inv};
    *(float4*)(orow + d) = o4;
  }
}

// ---------------- global-token full attention, one block per (head, g) ----------------
__global__ __launch_bounds__(256) void global_attn_kernel(
    const float* __restrict__ qkv, const int* __restrict__ amask,
    const int* __restrict__ gidx, const float* __restrict__ gvalid,
    float* __restrict__ outp) {
  int h = blockIdx.x / NG, g = blockIdx.x % NG;
  if (gvalid[g] <= 0.f) return;  // uniform across block
  int sg = gidx[g];
  __shared__ float qs[DH];
  __shared__ float sc[S];
  __shared__ float red[256];
  int t = threadIdx.x;
  if (t < DH) qs[t] = qkv[(size_t)sg * QKV3 + h * DH + t] * 0.125f;
  __syncthreads();
  float lmax = -1e30f;
  for (int ji = 0; ji < S / 256; ji++) {
    int j = ji * 256 + t;
    float s;
    if (amask[j] != 0) {
      s = 0.f;
      const float4* kr4 = (const float4*)(qkv + (size_t)j * QKV3 + HID + h * DH);
#pragma unroll
      for (int d4 = 0; d4 < 16; d4++) {
        float4 kv = kr4[d4];
        s += qs[d4 * 4] * kv.x + qs[d4 * 4 + 1] * kv.y +
             qs[d4 * 4 + 2] * kv.z + qs[d4 * 4 + 3] * kv.w;
      }
    } else s = NEGV;
    sc[j] = s;
    lmax = fmaxf(lmax, s);
  }
  float mm = block_reduce_max(lmax, red);
  float lsum = 0.f;
  for (int ji = 0; ji < S / 256; ji++) {
    int j = ji * 256 + t;
    float e = __expf(sc[j] - mm);
    sc[j] = e;
    lsum += e;
  }
  float denom = block_reduce_sum(lsum, red);
  int d = t & 63, grp = t >> 6;
  float o = 0.f;
  for (int j = grp; j < S; j += 4)
    o += sc[j] * qkv[(size_t)j * QKV3 + 2 * HID + h * DH + d];
  __syncthreads();
  red[grp * 64 + d] = o;
  __syncthreads();
  if (t < 64) {
    float oo = red[t] + red[64 + t] + red[128 + t] + red[192 + t];
    outp[(size_t)sg * HID + h * DH + t] = oo / denom;
  }
}

// ---------------- masked mean pool (partials) + classifier head ----------------
__global__ __launch_bounds__(256) void pool_part_kernel(
    const float* __restrict__ h, const int* __restrict__ amask, float* __restrict__ part) {
  int b = blockIdx.x, t = threadIdx.x;
  float a0 = 0.f, a1 = 0.f, a2 = 0.f;
  for (int r = 0; r < 64; r++) {
    int s = b * 64 + r;
    float w = (float)amask[s];
    const float* hr = h + (size_t)s * HID;
    a0 += hr[t] * w;
    a1 += hr[t + 256] * w;
    a2 += hr[t + 512] * w;
  }
  part[(size_t)b * HID + t] = a0;
  part[(size_t)b * HID + t + 256] = a1;
  part[(size_t)b * HID + t + 512] = a2;
}

__global__ __launch_bounds__(256) void cls_head_kernel(
    const float* __restrict__ part, const int* __restrict__ amask,
    const float* __restrict__ clsW, const float* __restrict__ clsb,
    float* __restrict__ out) {
  __shared__ float pooled[HID];
  __shared__ float red[256];
  int t = threadIdx.x;
  for (int i = t; i < HID; i += 256) {
    float s = 0.f;
    for (int b2 = 0; b2 < 64; b2++) s += part[(size_t)b2 * HID + i];
    pooled[i] = s;
  }
  float c = 0.f;
  for (int s2 = t; s2 < S; s2 += 256) c += (float)amask[s2];
  float cnt = block_reduce_sum(c, red);
  float p0 = 0.f, p1 = 0.f;
  for (int i = t; i < HID; i += 256) {
    float pv = pooled[i] / cnt;
    p0 += pv * clsW[i * 2];
    p1 += pv * clsW[i * 2 + 1];
  }
  float s0 = block_reduce_sum(p0, red);
  float s1 = block_reduce_sum(p1, red);
  if (t == 0) { out[0] = s0 + clsb[0]; out[1] = s1 + clsb[1]; }
}

// ---------------- launch ----------------
extern "C" void kernel_launch(void* const* d_in, const int* in_sizes, int n_in,
                              void* d_out, int out_size, void* d_ws, size_t ws_size,
                              hipStream_t stream) {
  const int* ids = (const int*)d_in[0];
  const int* amask = (const int*)d_in[1];
  const int* gmask = (const int*)d_in[2];
  const float* tok = (const float*)d_in[3];
  const float* pos = (const float*)d_in[4];
  const float* elnw = (const float*)d_in[5];
  const float* elnb = (const float*)d_in[6];
  const float* Wqkv = (const float*)d_in[7];
  const float* bqkv = (const float*)d_in[8];
  const float* Wo = (const float*)d_in[9];
  const float* bo = (const float*)d_in[10];
  const float* ln1w = (const float*)d_in[11];
  const float* ln1b = (const float*)d_in[12];
  const float* W1 = (const float*)d_in[13];
  const float* b1 = (const float*)d_in[14];
  const float* W2 = (const float*)d_in[15];
  const float* b2 = (const float*)d_in[16];
  const float* ln2w = (const float*)d_in[17];
  const float* ln2b = (const float*)d_in[18];
  const float* clsW = (const float*)d_in[19];
  const float* clsb = (const float*)d_in[20];

  float* ws = (float*)d_ws;
  float* h = ws;                              // S*HID
  float* buf = h + (size_t)S * HID;           // S*FF (qkv and ffn share)
  float* attn_o = buf + (size_t)S * FF;       // S*HID
  float* proj = attn_o + (size_t)S * HID;     // S*HID
  float* part = proj + (size_t)S * HID;       // 64*HID
  int* gidx = (int*)(part + 64 * HID);        // 16 ints
  float* gvalid = (float*)(gidx + NG);        // 16 floats
  // bf16 per-layer weight buffers (16B aligned: offset so far is 16B multiple)
  u16* WqkvT = (u16*)(gvalid + NG);           // QKV3*HID halves
  u16* WoT = WqkvT + (size_t)QKV3 * HID;      // HID*HID
  u16* W1T = WoT + (size_t)HID * HID;         // FF*HID
  u16* W2T = W1T + (size_t)FF * HID;          // HID*FF

  gidx_kernel<<<1, 64, 0, stream>>>(gmask, gidx, gvalid);
  embed_ln_kernel<<<S, 256, 0, stream>>>(ids, tok, pos, elnw, elnb, h);
  for (int l = 0; l < NLAYER; l++) {
    // convert this layer's weights to bf16, transposed to [N][K]
    wt_kernel<<<dim3(QKV3 / 32, HID / 32), 256, 0, stream>>>(
        Wqkv + (size_t)l * HID * QKV3, WqkvT, HID, QKV3);
    wt_kernel<<<dim3(HID / 32, HID / 32), 256, 0, stream>>>(
        Wo + (size_t)l * HID * HID, WoT, HID, HID);
    wt_kernel<<<dim3(FF / 32, HID / 32), 256, 0, stream>>>(
        W1 + (size_t)l * HID * FF, W1T, HID, FF);
    wt_kernel<<<dim3(HID / 32, FF / 32), 256, 0, stream>>>(
        W2 + (size_t)l * FF * HID, W2T, FF, HID);

    gemm_mfma_kernel<false><<<dim3(QKV3 / GBN, S / GBM), 256, 0, stream>>>(
        h, WqkvT, bqkv + (size_t)l * QKV3, buf, S, QKV3, HID);
    local_attn_kernel<<<NH * NC * 4, 64, 0, stream>>>(buf, amask, gmask, gidx, gvalid, attn_o);
    global_attn_kernel<<<NH * NG, 256, 0, stream>>>(buf, amask, gidx, gvalid, attn_o);
    gemm_mfma_kernel<false><<<dim3(HID / GBN, S / GBM), 256, 0, stream>>>(
        attn_o, WoT, bo + (size_t)l * HID, proj, S, HID, HID);
    add_ln_kernel<<<S, 256, 0, stream>>>(h, proj, ln1w + (size_t)l * HID, ln1b + (size_t)l * HID);
    gemm_mfma_kernel<true><<<dim3(FF / GBN, S / GBM), 256, 0, stream>>>(
        h, W1T, b1 + (size_t)l * FF, buf, S, FF, HID);
    gemm_mfma_kernel<false><<<dim3(HID / GBN, S / GBM), 256, 0, stream>>>(
        buf, W2T, b2 + (size_t)l * HID, proj, S, HID, FF);
    add_ln_kernel<<<S, 256, 0, stream>>>(h, proj, ln2w + (size_t)l * HID, ln2b + (size_t)l * HID);
  }
  pool_part_kernel<<<64, 256, 0, stream>>>(h, amask, part);
  cls_head_kernel<<<1, 256, 0, stream>>>(part, amask, clsW, clsb, (float*)d_out);
}

// Round 3
// 6004.334 us; speedup vs baseline: 3.4357x; 1.8474x over previous
//
#include <hip/hip_runtime.h>
#include <cmath>

#define S 4096
#define HID 768
#define NH 12
#define DH 64
#define CHUNK 256
#define NC (S / CHUNK)
#define NG 16
#define FF 3072
#define NLAYER 12
#define QKV3 (3 * HID)
#define NEGV -1e9f

typedef _Float16 f16;
typedef __attribute__((ext_vector_type(2))) _Float16 f16x2;
typedef __attribute__((ext_vector_type(4))) _Float16 f16x4;
typedef __attribute__((ext_vector_type(8))) _Float16 f16x8;
typedef __attribute__((ext_vector_type(4))) float f32x4;

__device__ __forceinline__ void async16(f16* lds, const f16* g) {
  __builtin_amdgcn_global_load_lds((const __attribute__((address_space(1))) unsigned int*)g,
                                   (__attribute__((address_space(3))) unsigned int*)lds,
                                   16, 0, 0);
}

// ---------------- block reduction helpers (blockDim.x == 256) ----------------
__device__ __forceinline__ float block_reduce_sum(float v, float* red) {
  int t = threadIdx.x;
  red[t] = v; __syncthreads();
  for (int st = 128; st > 0; st >>= 1) {
    if (t < st) red[t] += red[t + st];
    __syncthreads();
  }
  float r = red[0]; __syncthreads();
  return r;
}
__device__ __forceinline__ float block_reduce_max(float v, float* red) {
  int t = threadIdx.x;
  red[t] = v; __syncthreads();
  for (int st = 128; st > 0; st >>= 1) {
    if (t < st) red[t] = fmaxf(red[t], red[t + st]);
    __syncthreads();
  }
  float r = red[0]; __syncthreads();
  return r;
}

// ---------------- gidx / gvalid (matches jax top_k semantics) ----------------
__global__ void gidx_kernel(const int* __restrict__ gmask, int* __restrict__ gidx,
                            float* __restrict__ gvalid) {
  if (threadIdx.x != 0 || blockIdx.x != 0) return;
  int cnt = 0;
  for (int s = 0; s < S && cnt < NG; s++)
    if (gmask[s] > 0) { gidx[cnt] = s; gvalid[cnt] = 1.f; cnt++; }
  for (int s = 0; s < S && cnt < NG; s++)
    if (gmask[s] == 0) { gidx[cnt] = s; gvalid[cnt] = 0.f; cnt++; }
}

// ---------------- embedding + LayerNorm (writes f32 + f16) ----------------
__global__ __launch_bounds__(256) void embed_ln_kernel(
    const int* __restrict__ ids, const float* __restrict__ tok,
    const float* __restrict__ pos, const float* __restrict__ g,
    const float* __restrict__ b, float* __restrict__ h, f16* __restrict__ h16) {
  int s = blockIdx.x, t = threadIdx.x;
  __shared__ float xs[HID];
  __shared__ float red[256];
  const float* tr = tok + (size_t)ids[s] * HID;
  const float* pr = pos + (size_t)s * HID;
  float ls = 0.f;
  for (int i = t; i < HID; i += 256) { float v = tr[i] + pr[i]; xs[i] = v; ls += v; }
  float mu = block_reduce_sum(ls, red) * (1.f / HID);
  float lv = 0.f;
  for (int i = t; i < HID; i += 256) { float d = xs[i] - mu; lv += d * d; }
  float var = block_reduce_sum(lv, red) * (1.f / HID);
  float inv = rsqrtf(var + 1e-5f);
  for (int i = t; i < HID; i += 256) {
    float o = (xs[i] - mu) * inv * g[i] + b[i];
    h[(size_t)s * HID + i] = o;
    h16[(size_t)s * HID + i] = (f16)o;
  }
}

// ---------------- residual add + LayerNorm (in-place on h, also f16) ----------------
__global__ __launch_bounds__(256) void add_ln_kernel(
    float* __restrict__ h, const float* __restrict__ x2,
    const float* __restrict__ g, const float* __restrict__ b, f16* __restrict__ h16) {
  int s = blockIdx.x, t = threadIdx.x;
  __shared__ float xs[HID];
  __shared__ float red[256];
  float ls = 0.f;
  for (int i = t; i < HID; i += 256) {
    float v = h[(size_t)s * HID + i] + x2[(size_t)s * HID + i];
    xs[i] = v; ls += v;
  }
  float mu = block_reduce_sum(ls, red) * (1.f / HID);
  float lv = 0.f;
  for (int i = t; i < HID; i += 256) { float d = xs[i] - mu; lv += d * d; }
  float var = block_reduce_sum(lv, red) * (1.f / HID);
  float inv = rsqrtf(var + 1e-5f);
  for (int i = t; i < HID; i += 256) {
    float o = (xs[i] - mu) * inv * g[i] + b[i];
    h[(size_t)s * HID + i] = o;
    h16[(size_t)s * HID + i] = (f16)o;
  }
}

// ---------------- weight transpose + f16 convert: W[K][N] f32 -> WT[N][K] f16 ----
__global__ __launch_bounds__(256) void wt_kernel(const float* __restrict__ W,
                                                 f16* __restrict__ WT, int K, int N) {
  __shared__ float tile[32][33];
  int k0 = blockIdx.y * 32, n0 = blockIdx.x * 32;
  int t = threadIdx.x;
  int r = t >> 3, c = (t & 7) * 4;
  float4 v = *(const float4*)&W[(size_t)(k0 + r) * N + n0 + c];
  tile[r][c] = v.x; tile[r][c + 1] = v.y; tile[r][c + 2] = v.z; tile[r][c + 3] = v.w;
  __syncthreads();
  int n = t >> 3, kq = (t & 7) * 4;
  f16x4 o = {(f16)tile[kq][n], (f16)tile[kq + 1][n], (f16)tile[kq + 2][n], (f16)tile[kq + 3][n]};
  *(f16x4*)&WT[(size_t)(n0 + n) * K + k0 + kq] = o;
}

// ---------------- fp16 MFMA GEMM: C = A(f16,[M][K]) @ BT(f16,[N][K])^T + bias ------
#define GBM 128
#define GBN 128
#define GBK 64

template <int OMODE, bool GELU>  // OMODE 0: f32 out, 1: f16 out
__global__ __launch_bounds__(256) void gemm_f16_kernel(
    const f16* __restrict__ A, const f16* __restrict__ BT,
    const float* __restrict__ bias, void* __restrict__ Cout, int M, int N, int K) {
  __shared__ f16 As[GBM * GBK];  // rows of 64 halves (128B), chunk-XOR-swizzled
  __shared__ f16 Bs[GBN * GBK];
  int t = threadIdx.x, lane = t & 63, wave = t >> 6;
  int wr = wave >> 1, wc = wave & 1;
  int bx = blockIdx.x, by = blockIdx.y;

  f32x4 acc[4][4];
#pragma unroll
  for (int mi = 0; mi < 4; mi++)
#pragma unroll
    for (int ni = 0; ni < 4; ni++) acc[mi][ni] = (f32x4){0.f, 0.f, 0.f, 0.f};

  const f16* Ablk = A + (size_t)(by * GBM) * K;
  const f16* Bblk = BT + (size_t)(bx * GBN) * K;
  int rl = lane >> 3;             // row within 8-row group
  int lc = (lane & 7) ^ rl;       // pre-swizzled logical chunk for linear LDS dest

  for (int k0 = 0; k0 < K; k0 += GBK) {
#pragma unroll
    for (int ii = 0; ii < 4; ii++) {
      int i = wave * 4 + ii;
      int r = i * 8 + rl;
      async16(&As[i * 512], Ablk + (size_t)r * K + k0 + lc * 8);
      async16(&Bs[i * 512], Bblk + (size_t)r * K + k0 + lc * 8);
    }
    __syncthreads();
#pragma unroll
    for (int kc = 0; kc < 2; kc++) {
      f16x8 af[4], bf[4];
#pragma unroll
      for (int mi = 0; mi < 4; mi++) {
        int row = wr * 64 + mi * 16 + (lane & 15);
        int pc = (kc * 4 + (lane >> 4)) ^ (row & 7);
        af[mi] = *(const f16x8*)&As[row * 64 + pc * 8];
      }
#pragma unroll
      for (int ni = 0; ni < 4; ni++) {
        int row = wc * 64 + ni * 16 + (lane & 15);
        int pc = (kc * 4 + (lane >> 4)) ^ (row & 7);
        bf[ni] = *(const f16x8*)&Bs[row * 64 + pc * 8];
      }
#pragma unroll
      for (int mi = 0; mi < 4; mi++)
#pragma unroll
        for (int ni = 0; ni < 4; ni++)
          acc[mi][ni] = __builtin_amdgcn_mfma_f32_16x16x32_f16(af[mi], bf[ni], acc[mi][ni], 0, 0, 0);
    }
    __syncthreads();
  }

  int row_base = by * GBM + wr * 64 + (lane >> 4) * 4;
  int col_base = bx * GBN + wc * 64 + (lane & 15);
#pragma unroll
  for (int mi = 0; mi < 4; mi++) {
#pragma unroll
    for (int ni = 0; ni < 4; ni++) {
      int col = col_base + ni * 16;
      float bs = bias[col];
#pragma unroll
      for (int j = 0; j < 4; j++) {
        int row = row_base + mi * 16 + j;
        float x = acc[mi][ni][j] + bs;
        if (GELU) x = 0.5f * x * (1.f + erff(x * 0.70710678118654752f));
        if (OMODE == 0) ((float*)Cout)[(size_t)row * N + col] = x;
        else ((f16*)Cout)[(size_t)row * N + col] = (f16)x;
      }
    }
  }
}

// ---------------- MFMA local windowed attention ----------------
// block = (head, 64-query block), 256 threads = 4 waves, wave w owns q-cols 16w..16w+15
#define ROWP 72  // padded LDS row: 64 halves + 8 pad (144B) -> bank-spread, no swizzle

__global__ __launch_bounds__(256) void local_attn_mfma_kernel(
    const f16* __restrict__ qkv, const int* __restrict__ amask,
    const int* __restrict__ gmask, const int* __restrict__ gidx,
    const float* __restrict__ gvalid, f16* __restrict__ outp) {
  int h = blockIdx.x >> 6;
  int qb = blockIdx.x & 63;
  int q0 = qb * 64;
  int t = threadIdx.x, lane = t & 63, w = t >> 6;
  int g4 = lane >> 4, l15 = lane & 15;

  __shared__ f16 Qs[64 * ROWP];
  __shared__ f16 Kt[64 * ROWP];      // [k][d]
  __shared__ f16 Vt[64 * ROWP];      // [d][k]  (transposed)
  __shared__ f16 Pb[4 * 16 * ROWP];  // per-wave P^ rows [q][k]
  __shared__ unsigned kokLo, kokHi;
  __shared__ float gvs[NG];

  // ---- stage Q (scaled by 1/8), once ----
  {
    int r = t >> 2, c2 = (t & 3) * 2;
    const f16* qr = qkv + (size_t)(q0 + r) * QKV3 + h * DH + c2 * 8;
    f16x8 v0 = *(const f16x8*)qr;
    f16x8 v1 = *(const f16x8*)(qr + 8);
#pragma unroll
    for (int e = 0; e < 8; e++) { v0[e] = v0[e] * (f16)0.125f; v1[e] = v1[e] * (f16)0.125f; }
    *(f16x8*)&Qs[r * ROWP + c2 * 8] = v0;
    *(f16x8*)&Qs[r * ROWP + c2 * 8 + 8] = v1;
    if (t < NG) gvs[t] = gvalid[t];
  }
  __syncthreads();

  int qrow = w * 16 + l15;
  f16x8 qf0 = *(const f16x8*)&Qs[qrow * ROWP + g4 * 8];
  f16x8 qf1 = *(const f16x8*)&Qs[qrow * ROWP + 32 + g4 * 8];

  float mb = -50000.f, lp = 0.f;
  f32x4 oacc[4];
#pragma unroll
  for (int sd = 0; sd < 4; sd++) oacc[sd] = (f32x4){0.f, 0.f, 0.f, 0.f};

  f16* Pw = &Pb[w * 16 * ROWP];

  for (int kt = 0; kt <= 9; kt++) {
    int jb = q0 - 256 + kt * 64;
    bool isG = (kt == 9);
    if (!isG && (jb + 64 <= 0 || jb >= S)) continue;  // uniform across block
    __syncthreads();
    // ---- stage K tile [k][d] ----
    {
      int k = t >> 2, c2 = (t & 3) * 2;
      int j = isG ? (k < NG ? gidx[k] : -1) : (jb + k);
      bool jv = isG ? (k < NG && gvs[k] > 0.f) : (j >= 0 && j < S);
      f16x8 v0 = {}, v1 = {};
      if (jv) {
        const f16* kr = qkv + (size_t)j * QKV3 + HID + h * DH + c2 * 8;
        v0 = *(const f16x8*)kr; v1 = *(const f16x8*)(kr + 8);
      }
      *(f16x8*)&Kt[k * ROWP + c2 * 8] = v0;
      *(f16x8*)&Kt[k * ROWP + c2 * 8 + 8] = v1;
    }
    // ---- key-ok bitmask (wave 0) ----
    if (w == 0) {
      int k = lane;
      bool ok;
      if (isG) ok = (k < NG && gvs[k] > 0.f);
      else {
        int j = jb + k;
        ok = (j >= 0 && j < S) && (amask[j] != 0) && (gmask[j] == 0);
      }
      unsigned long long m = __ballot(ok);
      if (lane == 0) { kokLo = (unsigned)m; kokHi = (unsigned)(m >> 32); }
    }
    // ---- stage V transposed [d][k] ----
    {
      int k = t & 63, dq = (t >> 6) * 16;
      int j = isG ? (k < NG ? gidx[k] : -1) : (jb + k);
      bool jv = isG ? (k < NG && gvs[k] > 0.f) : (j >= 0 && j < S);
      f16x8 v0 = {}, v1 = {};
      if (jv) {
        const f16* vr = qkv + (size_t)j * QKV3 + 2 * HID + h * DH + dq;
        v0 = *(const f16x8*)vr; v1 = *(const f16x8*)(vr + 8);
      }
#pragma unroll
      for (int e = 0; e < 8; e++) {
        Vt[(dq + e) * ROWP + k] = v0[e];
        Vt[(dq + 8 + e) * ROWP + k] = v1[e];
      }
    }
    __syncthreads();

    unsigned long long kok = ((unsigned long long)kokHi << 32) | (unsigned long long)kokLo;

    // ---- QK^T (swapped): S^T[k][q] ----
    f32x4 sv[4];
#pragma unroll
    for (int s4 = 0; s4 < 4; s4++) {
      int krow = s4 * 16 + l15;
      f16x8 ka0 = *(const f16x8*)&Kt[krow * ROWP + g4 * 8];
      f16x8 ka1 = *(const f16x8*)&Kt[krow * ROWP + 32 + g4 * 8];
      f32x4 a = {0.f, 0.f, 0.f, 0.f};
      a = __builtin_amdgcn_mfma_f32_16x16x32_f16(ka0, qf0, a, 0, 0, 0);
      a = __builtin_amdgcn_mfma_f32_16x16x32_f16(ka1, qf1, a, 0, 0, 0);
      sv[s4] = a;
    }
    // ---- mask (key-ok + band edges on tiles 0/8) ----
    int ql = w * 16 + l15;
#pragma unroll
    for (int s4 = 0; s4 < 4; s4++)
#pragma unroll
      for (int r = 0; r < 4; r++) {
        int kl = s4 * 16 + g4 * 4 + r;
        bool ok = (kok >> kl) & 1ull;
        if (kt == 0) ok = ok && (kl >= ql);
        else if (kt == 8) ok = ok && (kl <= ql);
        sv[s4][r] = ok ? sv[s4][r] : -1e30f;
      }
    // ---- online softmax (per query column) ----
    float mt = -1e30f;
#pragma unroll
    for (int s4 = 0; s4 < 4; s4++)
#pragma unroll
      for (int r = 0; r < 4; r++) mt = fmaxf(mt, sv[s4][r]);
    mt = fmaxf(mt, __shfl_xor(mt, 16));
    mt = fmaxf(mt, __shfl_xor(mt, 32));
    float mn = fmaxf(mb, mt);
    float corr = __expf(mb - mn);
    mb = mn;
    lp *= corr;
#pragma unroll
    for (int sd = 0; sd < 4; sd++)
#pragma unroll
      for (int r = 0; r < 4; r++) oacc[sd][r] *= corr;
    // ---- p = exp(s-m), round to f16, store P^[q][k] ----
#pragma unroll
    for (int s4 = 0; s4 < 4; s4++) {
#pragma unroll
      for (int rp = 0; rp < 2; rp++) {
        float p0 = __expf(sv[s4][rp * 2] - mn);
        float p1 = __expf(sv[s4][rp * 2 + 1] - mn);
        f16 h0 = (f16)p0, h1 = (f16)p1;
        lp += (float)h0 + (float)h1;
        int kl = s4 * 16 + g4 * 4 + rp * 2;
        f16x2 pr = {h0, h1};
        *(f16x2*)&Pw[l15 * ROWP + kl] = pr;
      }
    }
    // ---- PV: O^T[d][q] += V^T @ P^T ----
    f16x8 pf0 = *(const f16x8*)&Pw[l15 * ROWP + g4 * 8];
    f16x8 pf1 = *(const f16x8*)&Pw[l15 * ROWP + 32 + g4 * 8];
#pragma unroll
    for (int sd = 0; sd < 4; sd++) {
      int drow = sd * 16 + l15;
      f16x8 va0 = *(const f16x8*)&Vt[drow * ROWP + g4 * 8];
      f16x8 va1 = *(const f16x8*)&Vt[drow * ROWP + 32 + g4 * 8];
      oacc[sd] = __builtin_amdgcn_mfma_f32_16x16x32_f16(va0, pf0, oacc[sd], 0, 0, 0);
      oacc[sd] = __builtin_amdgcn_mfma_f32_16x16x32_f16(va1, pf1, oacc[sd], 0, 0, 0);
    }
  }

  float lt = lp + __shfl_xor(lp, 16);
  lt = lt + __shfl_xor(lt, 32);
  float inv = (lt > 0.f) ? 1.f / lt : 0.f;
  int qg = q0 + w * 16 + l15;
  f16* orow = outp + (size_t)qg * HID + h * DH;
#pragma unroll
  for (int sd = 0; sd < 4; sd++)
#pragma unroll
    for (int r = 0; r < 4; r++)
      orow[sd * 16 + g4 * 4 + r] = (f16)(oacc[sd][r] * inv);
}

// ---------------- global-token full attention, one block per (head, g) ----------------
__global__ __launch_bounds__(256) void global_attn_kernel(
    const f16* __restrict__ qkv, const int* __restrict__ amask,
    const int* __restrict__ gidx, const float* __restrict__ gvalid,
    f16* __restrict__ outp) {
  int h = blockIdx.x / NG, g = blockIdx.x % NG;
  if (gvalid[g] <= 0.f) return;  // uniform across block
  int sg = gidx[g];
  __shared__ float qs[DH];
  __shared__ float sc[S];
  __shared__ float red[256];
  int t = threadIdx.x;
  if (t < DH) qs[t] = (float)qkv[(size_t)sg * QKV3 + h * DH + t] * 0.125f;
  __syncthreads();
  float lmax = -1e30f;
  for (int ji = 0; ji < S / 256; ji++) {
    int j = ji * 256 + t;
    float s;
    if (amask[j] != 0) {
      s = 0.f;
      const f16x8* kr = (const f16x8*)(qkv + (size_t)j * QKV3 + HID + h * DH);
#pragma unroll
      for (int c = 0; c < 8; c++) {
        f16x8 kv = kr[c];
#pragma unroll
        for (int e = 0; e < 8; e++) s += qs[c * 8 + e] * (float)kv[e];
      }
    } else s = NEGV;
    sc[j] = s;
    lmax = fmaxf(lmax, s);
  }
  float mm = block_reduce_max(lmax, red);
  float lsum = 0.f;
  for (int ji = 0; ji < S / 256; ji++) {
    int j = ji * 256 + t;
    float e = __expf(sc[j] - mm);
    sc[j] = e;
    lsum += e;
  }
  float denom = block_reduce_sum(lsum, red);
  int d = t & 63, grp = t >> 6;
  float o = 0.f;
  for (int j = grp; j < S; j += 4)
    o += sc[j] * (float)qkv[(size_t)j * QKV3 + 2 * HID + h * DH + d];
  __syncthreads();
  red[grp * 64 + d] = o;
  __syncthreads();
  if (t < 64) {
    float oo = red[t] + red[64 + t] + red[128 + t] + red[192 + t];
    outp[(size_t)sg * HID + h * DH + t] = (f16)(oo / denom);
  }
}

// ---------------- masked mean pool (partials) + classifier head ----------------
__global__ __launch_bounds__(256) void pool_part_kernel(
    const float* __restrict__ h, const int* __restrict__ amask, float* __restrict__ part) {
  int b = blockIdx.x, t = threadIdx.x;
  float a0 = 0.f, a1 = 0.f, a2 = 0.f;
  for (int r = 0; r < 64; r++) {
    int s = b * 64 + r;
    float w = (float)amask[s];
    const float* hr = h + (size_t)s * HID;
    a0 += hr[t] * w;
    a1 += hr[t + 256] * w;
    a2 += hr[t + 512] * w;
  }
  part[(size_t)b * HID + t] = a0;
  part[(size_t)b * HID + t + 256] = a1;
  part[(size_t)b * HID + t + 512] = a2;
}

__global__ __launch_bounds__(256) void cls_head_kernel(
    const float* __restrict__ part, const int* __restrict__ amask,
    const float* __restrict__ clsW, const float* __restrict__ clsb,
    float* __restrict__ out) {
  __shared__ float pooled[HID];
  __shared__ float red[256];
  int t = threadIdx.x;
  for (int i = t; i < HID; i += 256) {
    float s = 0.f;
    for (int b2 = 0; b2 < 64; b2++) s += part[(size_t)b2 * HID + i];
    pooled[i] = s;
  }
  float c = 0.f;
  for (int s2 = t; s2 < S; s2 += 256) c += (float)amask[s2];
  float cnt = block_reduce_sum(c, red);
  float p0 = 0.f, p1 = 0.f;
  for (int i = t; i < HID; i += 256) {
    float pv = pooled[i] / cnt;
    p0 += pv * clsW[i * 2];
    p1 += pv * clsW[i * 2 + 1];
  }
  float s0 = block_reduce_sum(p0, red);
  float s1 = block_reduce_sum(p1, red);
  if (t == 0) { out[0] = s0 + clsb[0]; out[1] = s1 + clsb[1]; }
}

// ---------------- launch ----------------
extern "C" void kernel_launch(void* const* d_in, const int* in_sizes, int n_in,
                              void* d_out, int out_size, void* d_ws, size_t ws_size,
                              hipStream_t stream) {
  const int* ids = (const int*)d_in[0];
  const int* amask = (const int*)d_in[1];
  const int* gmask = (const int*)d_in[2];
  const float* tok = (const float*)d_in[3];
  const float* pos = (const float*)d_in[4];
  const float* elnw = (const float*)d_in[5];
  const float* elnb = (const float*)d_in[6];
  const float* Wqkv = (const float*)d_in[7];
  const float* bqkv = (const float*)d_in[8];
  const float* Wo = (const float*)d_in[9];
  const float* bo = (const float*)d_in[10];
  const float* ln1w = (const float*)d_in[11];
  const float* ln1b = (const float*)d_in[12];
  const float* W1 = (const float*)d_in[13];
  const float* b1 = (const float*)d_in[14];
  const float* W2 = (const float*)d_in[15];
  const float* b2 = (const float*)d_in[16];
  const float* ln2w = (const float*)d_in[17];
  const float* ln2b = (const float*)d_in[18];
  const float* clsW = (const float*)d_in[19];
  const float* clsb = (const float*)d_in[20];

  char* w8 = (char*)d_ws;
  size_t o = 0;
  float* h = (float*)(w8 + o); o += (size_t)S * HID * 4;
  f16* h16 = (f16*)(w8 + o); o += (size_t)S * HID * 2;
  f16* qkv16 = (f16*)(w8 + o); o += (size_t)S * QKV3 * 2;
  f16* attn16 = (f16*)(w8 + o); o += (size_t)S * HID * 2;
  f16* ff16 = (f16*)(w8 + o); o += (size_t)S * FF * 2;
  float* proj = (float*)(w8 + o); o += (size_t)S * HID * 4;
  float* part = (float*)(w8 + o); o += (size_t)64 * HID * 4;
  int* gidx = (int*)(w8 + o); o += 64;
  float* gvalid = (float*)(w8 + o); o += 64;
  f16* WqkvT = (f16*)(w8 + o); o += (size_t)HID * QKV3 * 2;
  f16* WoT = (f16*)(w8 + o); o += (size_t)HID * HID * 2;
  f16* W1T = (f16*)(w8 + o); o += (size_t)HID * FF * 2;
  f16* W2T = (f16*)(w8 + o); o += (size_t)FF * HID * 2;

  gidx_kernel<<<1, 64, 0, stream>>>(gmask, gidx, gvalid);
  embed_ln_kernel<<<S, 256, 0, stream>>>(ids, tok, pos, elnw, elnb, h, h16);
  for (int l = 0; l < NLAYER; l++) {
    wt_kernel<<<dim3(QKV3 / 32, HID / 32), 256, 0, stream>>>(
        Wqkv + (size_t)l * HID * QKV3, WqkvT, HID, QKV3);
    wt_kernel<<<dim3(HID / 32, HID / 32), 256, 0, stream>>>(
        Wo + (size_t)l * HID * HID, WoT, HID, HID);
    wt_kernel<<<dim3(FF / 32, HID / 32), 256, 0, stream>>>(
        W1 + (size_t)l * HID * FF, W1T, HID, FF);
    wt_kernel<<<dim3(HID / 32, FF / 32), 256, 0, stream>>>(
        W2 + (size_t)l * FF * HID, W2T, FF, HID);

    gemm_f16_kernel<1, false><<<dim3(QKV3 / GBN, S / GBM), 256, 0, stream>>>(
        h16, WqkvT, bqkv + (size_t)l * QKV3, qkv16, S, QKV3, HID);
    local_attn_mfma_kernel<<<NH * 64, 256, 0, stream>>>(
        qkv16, amask, gmask, gidx, gvalid, attn16);
    global_attn_kernel<<<NH * NG, 256, 0, stream>>>(qkv16, amask, gidx, gvalid, attn16);
    gemm_f16_kernel<0, false><<<dim3(HID / GBN, S / GBM), 256, 0, stream>>>(
        attn16, WoT, bo + (size_t)l * HID, proj, S, HID, HID);
    add_ln_kernel<<<S, 256, 0, stream>>>(h, proj, ln1w + (size_t)l * HID,
                                         ln1b + (size_t)l * HID, h16);
    gemm_f16_kernel<1, true><<<dim3(FF / GBN, S / GBM), 256, 0, stream>>>(
        h16, W1T, b1 + (size_t)l * FF, ff16, S, FF, HID);
    gemm_f16_kernel<0, false><<<dim3(HID / GBN, S / GBM), 256, 0, stream>>>(
        ff16, W2T, b2 + (size_t)l * HID, proj, S, HID, FF);
    add_ln_kernel<<<S, 256, 0, stream>>>(h, proj, ln2w + (size_t)l * HID,
                                         ln2b + (size_t)l * HID, h16);
  }
  pool_part_kernel<<<64, 256, 0, stream>>>(h, amask, part);
  cls_head_kernel<<<1, 256, 0, stream>>>(part, amask, clsW, clsb, (float*)d_out);
}

// Round 4
// 3021.471 us; speedup vs baseline: 6.8275x; 1.9872x over previous
//
#include <hip/hip_runtime.h>
#include <cmath>

#define S 4096
#define HID 768
#define NH 12
#define DH 64
#define CHUNK 256
#define NC (S / CHUNK)
#define NG 16
#define FF 3072
#define NLAYER 12
#define QKV3 (3 * HID)
#define NEGV -1e9f

typedef _Float16 f16;
typedef __attribute__((ext_vector_type(2))) _Float16 f16x2;
typedef __attribute__((ext_vector_type(4))) _Float16 f16x4;
typedef __attribute__((ext_vector_type(8))) _Float16 f16x8;
typedef __attribute__((ext_vector_type(4))) float f32x4;

__device__ __forceinline__ void async16(f16* lds, const f16* g) {
  __builtin_amdgcn_global_load_lds((const __attribute__((address_space(1))) unsigned int*)g,
                                   (__attribute__((address_space(3))) unsigned int*)lds,
                                   16, 0, 0);
}

// ---------------- block reduction helpers (blockDim.x == 256) ----------------
__device__ __forceinline__ float block_reduce_sum(float v, float* red) {
  int t = threadIdx.x;
  red[t] = v; __syncthreads();
  for (int st = 128; st > 0; st >>= 1) {
    if (t < st) red[t] += red[t + st];
    __syncthreads();
  }
  float r = red[0]; __syncthreads();
  return r;
}
__device__ __forceinline__ float block_reduce_max(float v, float* red) {
  int t = threadIdx.x;
  red[t] = v; __syncthreads();
  for (int st = 128; st > 0; st >>= 1) {
    if (t < st) red[t] = fmaxf(red[t], red[t + st]);
    __syncthreads();
  }
  float r = red[0]; __syncthreads();
  return r;
}

// ---------------- gidx / gvalid (matches jax top_k semantics) ----------------
__global__ void gidx_kernel(const int* __restrict__ gmask, int* __restrict__ gidx,
                            float* __restrict__ gvalid) {
  if (threadIdx.x != 0 || blockIdx.x != 0) return;
  int cnt = 0;
  for (int s = 0; s < S && cnt < NG; s++)
    if (gmask[s] > 0) { gidx[cnt] = s; gvalid[cnt] = 1.f; cnt++; }
  for (int s = 0; s < S && cnt < NG; s++)
    if (gmask[s] == 0) { gidx[cnt] = s; gvalid[cnt] = 0.f; cnt++; }
}

// ---------------- embedding + LayerNorm (writes f32 + f16) ----------------
__global__ __launch_bounds__(256) void embed_ln_kernel(
    const int* __restrict__ ids, const float* __restrict__ tok,
    const float* __restrict__ pos, const float* __restrict__ g,
    const float* __restrict__ b, float* __restrict__ h, f16* __restrict__ h16) {
  int s = blockIdx.x, t = threadIdx.x;
  __shared__ float xs[HID];
  __shared__ float red[256];
  const float* tr = tok + (size_t)ids[s] * HID;
  const float* pr = pos + (size_t)s * HID;
  float ls = 0.f;
  for (int i = t; i < HID; i += 256) { float v = tr[i] + pr[i]; xs[i] = v; ls += v; }
  float mu = block_reduce_sum(ls, red) * (1.f / HID);
  float lv = 0.f;
  for (int i = t; i < HID; i += 256) { float d = xs[i] - mu; lv += d * d; }
  float var = block_reduce_sum(lv, red) * (1.f / HID);
  float inv = rsqrtf(var + 1e-5f);
  for (int i = t; i < HID; i += 256) {
    float o = (xs[i] - mu) * inv * g[i] + b[i];
    h[(size_t)s * HID + i] = o;
    h16[(size_t)s * HID + i] = (f16)o;
  }
}

// ---------------- residual add + LayerNorm (in-place on h, also f16) ----------------
__global__ __launch_bounds__(256) void add_ln_kernel(
    float* __restrict__ h, const float* __restrict__ x2,
    const float* __restrict__ g, const float* __restrict__ b, f16* __restrict__ h16) {
  int s = blockIdx.x, t = threadIdx.x;
  __shared__ float xs[HID];
  __shared__ float red[256];
  float ls = 0.f;
  for (int i = t; i < HID; i += 256) {
    float v = h[(size_t)s * HID + i] + x2[(size_t)s * HID + i];
    xs[i] = v; ls += v;
  }
  float mu = block_reduce_sum(ls, red) * (1.f / HID);
  float lv = 0.f;
  for (int i = t; i < HID; i += 256) { float d = xs[i] - mu; lv += d * d; }
  float var = block_reduce_sum(lv, red) * (1.f / HID);
  float inv = rsqrtf(var + 1e-5f);
  for (int i = t; i < HID; i += 256) {
    float o = (xs[i] - mu) * inv * g[i] + b[i];
    h[(size_t)s * HID + i] = o;
    h16[(size_t)s * HID + i] = (f16)o;
  }
}

// ---------------- weight transpose + f16 convert: W[K][N] f32 -> WT[N][K] f16 ----
__global__ __launch_bounds__(256) void wt_kernel(const float* __restrict__ W,
                                                 f16* __restrict__ WT, int K, int N) {
  __shared__ float tile[32][33];
  int k0 = blockIdx.y * 32, n0 = blockIdx.x * 32;
  int t = threadIdx.x;
  int r = t >> 3, c = (t & 7) * 4;
  float4 v = *(const float4*)&W[(size_t)(k0 + r) * N + n0 + c];
  tile[r][c] = v.x; tile[r][c + 1] = v.y; tile[r][c + 2] = v.z; tile[r][c + 3] = v.w;
  __syncthreads();
  int n = t >> 3, kq = (t & 7) * 4;
  f16x4 o = {(f16)tile[kq][n], (f16)tile[kq + 1][n], (f16)tile[kq + 2][n], (f16)tile[kq + 3][n]};
  *(f16x4*)&WT[(size_t)(n0 + n) * K + k0 + kq] = o;
}

// ---------------- fp16 MFMA GEMM: C = A(f16,[M][K]) @ BT(f16,[N][K])^T + bias ------
#define GBM 128
#define GBN 128
#define GBK 64

template <int OMODE, bool GELU>  // OMODE 0: f32 out, 1: f16 out
__global__ __launch_bounds__(256) void gemm_f16_kernel(
    const f16* __restrict__ A, const f16* __restrict__ BT,
    const float* __restrict__ bias, void* __restrict__ Cout, int M, int N, int K) {
  __shared__ f16 As[GBM * GBK];  // rows of 64 halves (128B), chunk-XOR-swizzled
  __shared__ f16 Bs[GBN * GBK];
  int t = threadIdx.x, lane = t & 63, wave = t >> 6;
  int wr = wave >> 1, wc = wave & 1;
  int bx = blockIdx.x, by = blockIdx.y;

  f32x4 acc[4][4];
#pragma unroll
  for (int mi = 0; mi < 4; mi++)
#pragma unroll
    for (int ni = 0; ni < 4; ni++) acc[mi][ni] = (f32x4){0.f, 0.f, 0.f, 0.f};

  const f16* Ablk = A + (size_t)(by * GBM) * K;
  const f16* Bblk = BT + (size_t)(bx * GBN) * K;
  int rl = lane >> 3;             // row within 8-row group
  int lc = (lane & 7) ^ rl;       // pre-swizzled logical chunk for linear LDS dest

  for (int k0 = 0; k0 < K; k0 += GBK) {
#pragma unroll
    for (int ii = 0; ii < 4; ii++) {
      int i = wave * 4 + ii;
      int r = i * 8 + rl;
      async16(&As[i * 512], Ablk + (size_t)r * K + k0 + lc * 8);
      async16(&Bs[i * 512], Bblk + (size_t)r * K + k0 + lc * 8);
    }
    __syncthreads();
#pragma unroll
    for (int kc = 0; kc < 2; kc++) {
      f16x8 af[4], bf[4];
#pragma unroll
      for (int mi = 0; mi < 4; mi++) {
        int row = wr * 64 + mi * 16 + (lane & 15);
        int pc = (kc * 4 + (lane >> 4)) ^ (row & 7);
        af[mi] = *(const f16x8*)&As[row * 64 + pc * 8];
      }
#pragma unroll
      for (int ni = 0; ni < 4; ni++) {
        int row = wc * 64 + ni * 16 + (lane & 15);
        int pc = (kc * 4 + (lane >> 4)) ^ (row & 7);
        bf[ni] = *(const f16x8*)&Bs[row * 64 + pc * 8];
      }
#pragma unroll
      for (int mi = 0; mi < 4; mi++)
#pragma unroll
        for (int ni = 0; ni < 4; ni++)
          acc[mi][ni] = __builtin_amdgcn_mfma_f32_16x16x32_f16(af[mi], bf[ni], acc[mi][ni], 0, 0, 0);
    }
    __syncthreads();
  }

  int row_base = by * GBM + wr * 64 + (lane >> 4) * 4;
  int col_base = bx * GBN + wc * 64 + (lane & 15);
#pragma unroll
  for (int mi = 0; mi < 4; mi++) {
#pragma unroll
    for (int ni = 0; ni < 4; ni++) {
      int col = col_base + ni * 16;
      float bs = bias[col];
#pragma unroll
      for (int j = 0; j < 4; j++) {
        int row = row_base + mi * 16 + j;
        float x = acc[mi][ni][j] + bs;
        if (GELU) x = 0.5f * x * (1.f + erff(x * 0.70710678118654752f));
        if (OMODE == 0) ((float*)Cout)[(size_t)row * N + col] = x;
        else ((f16*)Cout)[(size_t)row * N + col] = (f16)x;
      }
    }
  }
}

// ---------------- MFMA local windowed attention ----------------
// block = (head, 64-query block), 256 threads = 4 waves, wave w owns q-cols 16w..16w+15
#define ROWP 72  // padded LDS row: 64 halves + 8 pad (144B) -> bank-spread, no swizzle

__global__ __launch_bounds__(256) void local_attn_mfma_kernel(
    const f16* __restrict__ qkv, const int* __restrict__ amask,
    const int* __restrict__ gmask, const int* __restrict__ gidx,
    const float* __restrict__ gvalid, f16* __restrict__ outp) {
  int h = blockIdx.x >> 6;
  int qb = blockIdx.x & 63;
  int q0 = qb * 64;
  int t = threadIdx.x, lane = t & 63, w = t >> 6;
  int g4 = lane >> 4, l15 = lane & 15;

  __shared__ f16 Qs[64 * ROWP];
  __shared__ f16 Kt[64 * ROWP];      // [k][d]
  __shared__ f16 Vt[64 * ROWP];      // [d][k]  (transposed)
  __shared__ f16 Pb[4 * 16 * ROWP];  // per-wave P^ rows [q][k]
  __shared__ unsigned kokLo, kokHi;
  __shared__ float gvs[NG];

  // ---- stage Q (scaled by 1/8), once ----
  {
    int r = t >> 2, c2 = (t & 3) * 2;
    const f16* qr = qkv + (size_t)(q0 + r) * QKV3 + h * DH + c2 * 8;
    f16x8 v0 = *(const f16x8*)qr;
    f16x8 v1 = *(const f16x8*)(qr + 8);
#pragma unroll
    for (int e = 0; e < 8; e++) { v0[e] = v0[e] * (f16)0.125f; v1[e] = v1[e] * (f16)0.125f; }
    *(f16x8*)&Qs[r * ROWP + c2 * 8] = v0;
    *(f16x8*)&Qs[r * ROWP + c2 * 8 + 8] = v1;
    if (t < NG) gvs[t] = gvalid[t];
  }
  __syncthreads();

  int qrow = w * 16 + l15;
  f16x8 qf0 = *(const f16x8*)&Qs[qrow * ROWP + g4 * 8];
  f16x8 qf1 = *(const f16x8*)&Qs[qrow * ROWP + 32 + g4 * 8];

  float mb = -50000.f, lp = 0.f;
  f32x4 oacc[4];
#pragma unroll
  for (int sd = 0; sd < 4; sd++) oacc[sd] = (f32x4){0.f, 0.f, 0.f, 0.f};

  f16* Pw = &Pb[w * 16 * ROWP];

  for (int kt = 0; kt <= 9; kt++) {
    int jb = q0 - 256 + kt * 64;
    bool isG = (kt == 9);
    if (!isG && (jb + 64 <= 0 || jb >= S)) continue;  // uniform across block
    __syncthreads();
    // ---- stage K tile [k][d] ----
    {
      int k = t >> 2, c2 = (t & 3) * 2;
      int j = isG ? (k < NG ? gidx[k] : -1) : (jb + k);
      bool jv = isG ? (k < NG && gvs[k] > 0.f) : (j >= 0 && j < S);
      f16x8 v0 = {}, v1 = {};
      if (jv) {
        const f16* kr = qkv + (size_t)j * QKV3 + HID + h * DH + c2 * 8;
        v0 = *(const f16x8*)kr; v1 = *(const f16x8*)(kr + 8);
      }
      *(f16x8*)&Kt[k * ROWP + c2 * 8] = v0;
      *(f16x8*)&Kt[k * ROWP + c2 * 8 + 8] = v1;
    }
    // ---- key-ok bitmask (wave 0) ----
    if (w == 0) {
      int k = lane;
      bool ok;
      if (isG) ok = (k < NG && gvs[k] > 0.f);
      else {
        int j = jb + k;
        ok = (j >= 0 && j < S) && (amask[j] != 0) && (gmask[j] == 0);
      }
      unsigned long long m = __ballot(ok);
      if (lane == 0) { kokLo = (unsigned)m; kokHi = (unsigned)(m >> 32); }
    }
    // ---- stage V transposed [d][k] ----
    {
      int k = t & 63, dq = (t >> 6) * 16;
      int j = isG ? (k < NG ? gidx[k] : -1) : (jb + k);
      bool jv = isG ? (k < NG && gvs[k] > 0.f) : (j >= 0 && j < S);
      f16x8 v0 = {}, v1 = {};
      if (jv) {
        const f16* vr = qkv + (size_t)j * QKV3 + 2 * HID + h * DH + dq;
        v0 = *(const f16x8*)vr; v1 = *(const f16x8*)(vr + 8);
      }
#pragma unroll
      for (int e = 0; e < 8; e++) {
        Vt[(dq + e) * ROWP + k] = v0[e];
        Vt[(dq + 8 + e) * ROWP + k] = v1[e];
      }
    }
    __syncthreads();

    unsigned long long kok = ((unsigned long long)kokHi << 32) | (unsigned long long)kokLo;

    // ---- QK^T (swapped): S^T[k][q] ----
    f32x4 sv[4];
#pragma unroll
    for (int s4 = 0; s4 < 4; s4++) {
      int krow = s4 * 16 + l15;
      f16x8 ka0 = *(const f16x8*)&Kt[krow * ROWP + g4 * 8];
      f16x8 ka1 = *(const f16x8*)&Kt[krow * ROWP + 32 + g4 * 8];
      f32x4 a = {0.f, 0.f, 0.f, 0.f};
      a = __builtin_amdgcn_mfma_f32_16x16x32_f16(ka0, qf0, a, 0, 0, 0);
      a = __builtin_amdgcn_mfma_f32_16x16x32_f16(ka1, qf1, a, 0, 0, 0);
      sv[s4] = a;
    }
    // ---- mask (key-ok + band edges on tiles 0/8) ----
    int ql = w * 16 + l15;
#pragma unroll
    for (int s4 = 0; s4 < 4; s4++)
#pragma unroll
      for (int r = 0; r < 4; r++) {
        int kl = s4 * 16 + g4 * 4 + r;
        bool ok = (kok >> kl) & 1ull;
        if (kt == 0) ok = ok && (kl >= ql);
        else if (kt == 8) ok = ok && (kl <= ql);
        sv[s4][r] = ok ? sv[s4][r] : -1e30f;
      }
    // ---- online softmax (per query column) ----
    float mt = -1e30f;
#pragma unroll
    for (int s4 = 0; s4 < 4; s4++)
#pragma unroll
      for (int r = 0; r < 4; r++) mt = fmaxf(mt, sv[s4][r]);
    mt = fmaxf(mt, __shfl_xor(mt, 16));
    mt = fmaxf(mt, __shfl_xor(mt, 32));
    float mn = fmaxf(mb, mt);
    float corr = __expf(mb - mn);
    mb = mn;
    lp *= corr;
#pragma unroll
    for (int sd = 0; sd < 4; sd++)
#pragma unroll
      for (int r = 0; r < 4; r++) oacc[sd][r] *= corr;
    // ---- p = exp(s-m), round to f16, store P^[q][k] ----
#pragma unroll
    for (int s4 = 0; s4 < 4; s4++) {
#pragma unroll
      for (int rp = 0; rp < 2; rp++) {
        float p0 = __expf(sv[s4][rp * 2] - mn);
        float p1 = __expf(sv[s4][rp * 2 + 1] - mn);
        f16 h0 = (f16)p0, h1 = (f16)p1;
        lp += (float)h0 + (float)h1;
        int kl = s4 * 16 + g4 * 4 + rp * 2;
        f16x2 pr = {h0, h1};
        *(f16x2*)&Pw[l15 * ROWP + kl] = pr;
      }
    }
    // ---- PV: O^T[d][q] += V^T @ P^T ----
    f16x8 pf0 = *(const f16x8*)&Pw[l15 * ROWP + g4 * 8];
    f16x8 pf1 = *(const f16x8*)&Pw[l15 * ROWP + 32 + g4 * 8];
#pragma unroll
    for (int sd = 0; sd < 4; sd++) {
      int drow = sd * 16 + l15;
      f16x8 va0 = *(const f16x8*)&Vt[drow * ROWP + g4 * 8];
      f16x8 va1 = *(const f16x8*)&Vt[drow * ROWP + 32 + g4 * 8];
      oacc[sd] = __builtin_amdgcn_mfma_f32_16x16x32_f16(va0, pf0, oacc[sd], 0, 0, 0);
      oacc[sd] = __builtin_amdgcn_mfma_f32_16x16x32_f16(va1, pf1, oacc[sd], 0, 0, 0);
    }
  }

  float lt = lp + __shfl_xor(lp, 16);
  lt = lt + __shfl_xor(lt, 32);
  float inv = (lt > 0.f) ? 1.f / lt : 0.f;
  int qg = q0 + w * 16 + l15;
  f16* orow = outp + (size_t)qg * HID + h * DH;
#pragma unroll
  for (int sd = 0; sd < 4; sd++)
#pragma unroll
    for (int r = 0; r < 4; r++)
      orow[sd * 16 + g4 * 4 + r] = (f16)(oacc[sd][r] * inv);
}

// ============ global-token attention, split-K pipeline ============
// GA1: scores. grid = NH*16, block per (h, 256-key chunk). Sg[h][g][j] f32.
__global__ __launch_bounds__(256) void gscore_kernel(
    const f16* __restrict__ qkv, const int* __restrict__ amask,
    const int* __restrict__ gidx, float* __restrict__ Sg) {
  int h = blockIdx.x >> 4, jc = blockIdx.x & 15;
  int t = threadIdx.x;
  __shared__ f16 Qs[NG][DH];
  if (t < 128) {
    int g = t >> 3, c = (t & 7) * 8;
    const f16* qr = qkv + (size_t)gidx[g] * QKV3 + h * DH + c;
    *(f16x8*)&Qs[g][c] = *(const f16x8*)qr;
  }
  __syncthreads();
  int j = jc * 256 + t;
  const f16x8* kr = (const f16x8*)(qkv + (size_t)j * QKV3 + HID + h * DH);
  f16x8 kv[8];
#pragma unroll
  for (int c = 0; c < 8; c++) kv[c] = kr[c];
  bool ok = amask[j] != 0;
#pragma unroll 4
  for (int g = 0; g < NG; g++) {
    float s = 0.f;
#pragma unroll
    for (int c = 0; c < 8; c++) {
      f16x8 qv = *(const f16x8*)&Qs[g][c * 8];
#pragma unroll
      for (int e = 0; e < 8; e++) s += (float)qv[e] * (float)kv[c][e];
    }
    Sg[(size_t)(h * NG + g) * S + j] = ok ? s * 0.125f : NEGV;
  }
}

// GA2: per-(h,g) softmax stats (max, denom). grid = NH*NG.
__global__ __launch_bounds__(256) void gstat_kernel(const float* __restrict__ Sg,
                                                    float* __restrict__ stats) {
  int hg = blockIdx.x;
  const float* row = Sg + (size_t)hg * S;
  __shared__ float red[256];
  int t = threadIdx.x;
  float m = -1e30f;
  for (int j = t; j < S; j += 256) m = fmaxf(m, row[j]);
  m = block_reduce_max(m, red);
  float sum = 0.f;
  for (int j = t; j < S; j += 256) sum += __expf(row[j] - m);
  sum = block_reduce_sum(sum, red);
  if (t == 0) { stats[hg * 2] = m; stats[hg * 2 + 1] = sum; }
}

// GA3: PV split-K partials. grid = NH*16, block per (h, 256-key chunk).
// part[h][g][jc][d] f32
__global__ __launch_bounds__(256) void gpv_kernel(
    const f16* __restrict__ qkv, const float* __restrict__ Sg,
    const float* __restrict__ stats, float* __restrict__ part) {
  int h = blockIdx.x >> 4, jc = blockIdx.x & 15;
  int jb = jc * 256;
  int t = threadIdx.x;
  __shared__ float Ps[NG][256];
  __shared__ f16 Vs[256][DH];
#pragma unroll
  for (int g = 0; g < NG; g++) {
    int hg = h * NG + g;
    float m = stats[hg * 2], inv = 1.f / stats[hg * 2 + 1];
    Ps[g][t] = __expf(Sg[(size_t)hg * S + jb + t] - m) * inv;
  }
  {
    int r = t >> 3, c = (t & 7) * 8;
#pragma unroll
    for (int pp = 0; pp < 8; pp++) {
      int row = pp * 32 + r;
      const f16* vr = qkv + (size_t)(jb + row) * QKV3 + 2 * HID + h * DH + c;
      *(f16x8*)&Vs[row][c] = *(const f16x8*)vr;
    }
  }
  __syncthreads();
  int d = t & 63, g4 = t >> 6;
  float o0 = 0.f, o1 = 0.f, o2 = 0.f, o3 = 0.f;
#pragma unroll 8
  for (int j = 0; j < 256; j++) {
    float v = (float)Vs[j][d];
    o0 += Ps[g4][j] * v;
    o1 += Ps[g4 + 4][j] * v;
    o2 += Ps[g4 + 8][j] * v;
    o3 += Ps[g4 + 12][j] * v;
  }
  size_t base = ((size_t)h * NG) * 16 * 64;
  part[base + ((size_t)(g4) * 16 + jc) * 64 + d] = o0;
  part[base + ((size_t)(g4 + 4) * 16 + jc) * 64 + d] = o1;
  part[base + ((size_t)(g4 + 8) * 16 + jc) * 64 + d] = o2;
  part[base + ((size_t)(g4 + 12) * 16 + jc) * 64 + d] = o3;
}

// GA4: reduce partials, overwrite valid global rows. grid = NH*NG, 64 threads.
__global__ __launch_bounds__(64) void gout_kernel(
    const float* __restrict__ part, const int* __restrict__ gidx,
    const float* __restrict__ gvalid, f16* __restrict__ attn16) {
  int h = blockIdx.x >> 4, g = blockIdx.x & 15;
  if (gvalid[g] <= 0.f) return;
  int d = threadIdx.x;
  const float* pr = part + (((size_t)(h * NG + g)) * 16) * 64 + d;
  float s = 0.f;
#pragma unroll
  for (int jc = 0; jc < 16; jc++) s += pr[jc * 64];
  attn16[(size_t)gidx[g] * HID + h * DH + d] = (f16)s;
}

// ---------------- masked mean pool (partials) + classifier head ----------------
__global__ __launch_bounds__(256) void pool_part_kernel(
    const float* __restrict__ h, const int* __restrict__ amask, float* __restrict__ part) {
  int b = blockIdx.x, t = threadIdx.x;
  float a0 = 0.f, a1 = 0.f, a2 = 0.f;
  for (int r = 0; r < 64; r++) {
    int s = b * 64 + r;
    float w = (float)amask[s];
    const float* hr = h + (size_t)s * HID;
    a0 += hr[t] * w;
    a1 += hr[t + 256] * w;
    a2 += hr[t + 512] * w;
  }
  part[(size_t)b * HID + t] = a0;
  part[(size_t)b * HID + t + 256] = a1;
  part[(size_t)b * HID + t + 512] = a2;
}

__global__ __launch_bounds__(256) void cls_head_kernel(
    const float* __restrict__ part, const int* __restrict__ amask,
    const float* __restrict__ clsW, const float* __restrict__ clsb,
    float* __restrict__ out) {
  __shared__ float pooled[HID];
  __shared__ float red[256];
  int t = threadIdx.x;
  for (int i = t; i < HID; i += 256) {
    float s = 0.f;
    for (int b2 = 0; b2 < 64; b2++) s += part[(size_t)b2 * HID + i];
    pooled[i] = s;
  }
  float c = 0.f;
  for (int s2 = t; s2 < S; s2 += 256) c += (float)amask[s2];
  float cnt = block_reduce_sum(c, red);
  float p0 = 0.f, p1 = 0.f;
  for (int i = t; i < HID; i += 256) {
    float pv = pooled[i] / cnt;
    p0 += pv * clsW[i * 2];
    p1 += pv * clsW[i * 2 + 1];
  }
  float s0 = block_reduce_sum(p0, red);
  float s1 = block_reduce_sum(p1, red);
  if (t == 0) { out[0] = s0 + clsb[0]; out[1] = s1 + clsb[1]; }
}

// ---------------- launch ----------------
extern "C" void kernel_launch(void* const* d_in, const int* in_sizes, int n_in,
                              void* d_out, int out_size, void* d_ws, size_t ws_size,
                              hipStream_t stream) {
  const int* ids = (const int*)d_in[0];
  const int* amask = (const int*)d_in[1];
  const int* gmask = (const int*)d_in[2];
  const float* tok = (const float*)d_in[3];
  const float* pos = (const float*)d_in[4];
  const float* elnw = (const float*)d_in[5];
  const float* elnb = (const float*)d_in[6];
  const float* Wqkv = (const float*)d_in[7];
  const float* bqkv = (const float*)d_in[8];
  const float* Wo = (const float*)d_in[9];
  const float* bo = (const float*)d_in[10];
  const float* ln1w = (const float*)d_in[11];
  const float* ln1b = (const float*)d_in[12];
  const float* W1 = (const float*)d_in[13];
  const float* b1 = (const float*)d_in[14];
  const float* W2 = (const float*)d_in[15];
  const float* b2 = (const float*)d_in[16];
  const float* ln2w = (const float*)d_in[17];
  const float* ln2b = (const float*)d_in[18];
  const float* clsW = (const float*)d_in[19];
  const float* clsb = (const float*)d_in[20];

  char* w8 = (char*)d_ws;
  size_t o = 0;
  float* h = (float*)(w8 + o); o += (size_t)S * HID * 4;
  f16* h16 = (f16*)(w8 + o); o += (size_t)S * HID * 2;
  f16* qkv16 = (f16*)(w8 + o); o += (size_t)S * QKV3 * 2;
  f16* attn16 = (f16*)(w8 + o); o += (size_t)S * HID * 2;
  f16* ff16 = (f16*)(w8 + o); o += (size_t)S * FF * 2;
  float* proj = (float*)(w8 + o); o += (size_t)S * HID * 4;
  float* part = (float*)(w8 + o); o += (size_t)64 * HID * 4;
  int* gidx = (int*)(w8 + o); o += 64;
  float* gvalid = (float*)(w8 + o); o += 64;
  f16* WqkvT = (f16*)(w8 + o); o += (size_t)HID * QKV3 * 2;
  f16* WoT = (f16*)(w8 + o); o += (size_t)HID * HID * 2;
  f16* W1T = (f16*)(w8 + o); o += (size_t)HID * FF * 2;
  f16* W2T = (f16*)(w8 + o); o += (size_t)FF * HID * 2;
  float* Sg = (float*)(w8 + o); o += (size_t)NH * NG * S * 4;
  float* gstats = (float*)(w8 + o); o += (size_t)NH * NG * 2 * 4;
  float* gpart = (float*)(w8 + o); o += (size_t)NH * NG * 16 * 64 * 4;

  gidx_kernel<<<1, 64, 0, stream>>>(gmask, gidx, gvalid);
  embed_ln_kernel<<<S, 256, 0, stream>>>(ids, tok, pos, elnw, elnb, h, h16);
  for (int l = 0; l < NLAYER; l++) {
    wt_kernel<<<dim3(QKV3 / 32, HID / 32), 256, 0, stream>>>(
        Wqkv + (size_t)l * HID * QKV3, WqkvT, HID, QKV3);
    wt_kernel<<<dim3(HID / 32, HID / 32), 256, 0, stream>>>(
        Wo + (size_t)l * HID * HID, WoT, HID, HID);
    wt_kernel<<<dim3(FF / 32, HID / 32), 256, 0, stream>>>(
        W1 + (size_t)l * HID * FF, W1T, HID, FF);
    wt_kernel<<<dim3(HID / 32, FF / 32), 256, 0, stream>>>(
        W2 + (size_t)l * FF * HID, W2T, FF, HID);

    gemm_f16_kernel<1, false><<<dim3(QKV3 / GBN, S / GBM), 256, 0, stream>>>(
        h16, WqkvT, bqkv + (size_t)l * QKV3, qkv16, S, QKV3, HID);
    local_attn_mfma_kernel<<<NH * 64, 256, 0, stream>>>(
        qkv16, amask, gmask, gidx, gvalid, attn16);
    gscore_kernel<<<NH * 16, 256, 0, stream>>>(qkv16, amask, gidx, Sg);
    gstat_kernel<<<NH * NG, 256, 0, stream>>>(Sg, gstats);
    gpv_kernel<<<NH * 16, 256, 0, stream>>>(qkv16, Sg, gstats, gpart);
    gout_kernel<<<NH * NG, 64, 0, stream>>>(gpart, gidx, gvalid, attn16);
    gemm_f16_kernel<0, false><<<dim3(HID / GBN, S / GBM), 256, 0, stream>>>(
        attn16, WoT, bo + (size_t)l * HID, proj, S, HID, HID);
    add_ln_kernel<<<S, 256, 0, stream>>>(h, proj, ln1w + (size_t)l * HID,
                                         ln1b + (size_t)l * HID, h16);
    gemm_f16_kernel<1, true><<<dim3(FF / GBN, S / GBM), 256, 0, stream>>>(
        h16, W1T, b1 + (size_t)l * FF, ff16, S, FF, HID);
    gemm_f16_kernel<0, false><<<dim3(HID / GBN, S / GBM), 256, 0, stream>>>(
        ff16, W2T, b2 + (size_t)l * HID, proj, S, HID, FF);
    add_ln_kernel<<<S, 256, 0, stream>>>(h, proj, ln2w + (size_t)l * HID,
                                         ln2b + (size_t)l * HID, h16);
  }
  pool_part_kernel<<<64, 256, 0, stream>>>(h, amask, part);
  cls_head_kernel<<<1, 256, 0, stream>>>(part, amask, clsW, clsb, (float*)d_out);
}